// Round 6
// baseline (132.479 us; speedup 1.0000x reference)
//
#include <hip/hip_runtime.h>
#include <hip/hip_cooperative_groups.h>

namespace cg = cooperative_groups;

typedef __attribute__((ext_vector_type(8))) short short8v;   // 8 bf16
typedef __attribute__((ext_vector_type(4))) float f32x4;

// fp32 -> bf16 RNE (scalar)
__device__ __forceinline__ unsigned short f2bf(float f) {
    union { float f; unsigned u; } v; v.f = f;
    unsigned u = v.u;
    return (unsigned short)((u + 0x7FFFu + ((u >> 16) & 1u)) >> 16);
}
__device__ __forceinline__ float bf2f(unsigned short u) {
    union { unsigned u; float f; } v; v.u = ((unsigned)u) << 16; return v.f;
}
// 8 consecutive fp32 -> bf16x8 fragment via v_cvt_pk_bf16_f32
__device__ __forceinline__ short8v cvt8(const float* p) {
    float4 lo = *(const float4*)p;
    float4 hi = *(const float4*)(p + 4);
    union { uint4 u; short8v s; } r;
    asm("v_cvt_pk_bf16_f32 %0, %1, %2" : "=v"(r.u.x) : "v"(lo.x), "v"(lo.y));
    asm("v_cvt_pk_bf16_f32 %0, %1, %2" : "=v"(r.u.y) : "v"(lo.z), "v"(lo.w));
    asm("v_cvt_pk_bf16_f32 %0, %1, %2" : "=v"(r.u.z) : "v"(hi.x), "v"(hi.y));
    asm("v_cvt_pk_bf16_f32 %0, %1, %2" : "=v"(r.u.w) : "v"(hi.z), "v"(hi.w));
    return r.s;
}
__device__ __forceinline__ short8v ld8(const unsigned short* p) {
    return *(const short8v*)p;
}

struct GigaParams {
    const float *async_fea, *sync_fea;
    const int *async_adj, *sync_adj;
    const float *aWq, *abq, *aWk, *abk, *aWv, *abv, *aWo, *abo, *aWm, *abm;
    const float *sWq, *sbq, *sWk, *sbk, *sWv, *sbv, *sWo, *sbo, *sWm, *sbm;
    unsigned short *Qb, *Kb, *VT, *Wcb, *Eg;
    float *bc;
    float *out;
};

__global__ __launch_bounds__(384) void giga_kernel(GigaParams p)
{
    __shared__ unsigned short E_l[8 * 48 * 50];   // bf16, row stride 50
    __shared__ float msk[12 * 48];
    __shared__ float invd[12 * 384];
    __shared__ unsigned short yv_b[16 * 520];     // [tt pad16][h*64+k pad], bf16
    __shared__ unsigned short P_lds[16 * 264];    // bf16
    __shared__ float cnt_l[12];

    const int bid = blockIdx.x, tid = threadIdx.x;
    const int wave = tid >> 6, lane = tid & 63;
    const int l15 = lane & 15, g = lane >> 4, l16 = g << 3;
    const int w = bid * 6 + wave;                 // global wave id 0..1535

    // ================= Phase 0: QKV projections + fold =================
    // jobs: 0..767 Q, 768..1535 K, 1536..2303 V, 2304..2431 fold
    #pragma unroll
    for (int rep = 0; rep < 2; ++rep) {
        int job = w + rep * 1536;
        if (job >= 2432) break;
        if (job < 2304) {
            int t = job / 768;
            int r = job % 768;
            int agg = r / 384, rr = r % 384;
            int rowtile = rr >> 2, coltile = rr & 3;
            int row0 = rowtile * 16, col0 = coltile * 64;
            const float* X = agg ? p.async_fea : p.sync_fea;
            const float* W; const float* bias;
            if (agg == 0) {
                W    = (t == 0) ? p.aWq : (t == 1) ? p.aWk : p.aWv;
                bias = (t == 0) ? p.abq : (t == 1) ? p.abk : p.abv;
            } else {
                W    = (t == 0) ? p.sWq : (t == 1) ? p.sWk : p.sWv;
                bias = (t == 0) ? p.sbq : (t == 1) ? p.sbk : p.sbv;
            }
            const float* Xp = X + (row0 + l15) * 256 + l16;
            const float* Wp = W + (col0 + l15) * 256 + l16;
            f32x4 acc[4] = {{0,0,0,0},{0,0,0,0},{0,0,0,0},{0,0,0,0}};
            #pragma unroll
            for (int kk = 0; kk < 8; ++kk) {
                short8v a = cvt8(Xp + kk * 32);
                #pragma unroll
                for (int j = 0; j < 4; ++j) {
                    short8v b = cvt8(Wp + j * 16 * 256 + kk * 32);
                    acc[j] = __builtin_amdgcn_mfma_f32_16x16x32_bf16(a, b, acc[j], 0, 0, 0);
                }
            }
            if (t < 2) {
                unsigned short* dst = (t == 0 ? p.Qb : p.Kb) + agg * 393216;
                #pragma unroll
                for (int j = 0; j < 4; ++j) {
                    int c = col0 + j * 16 + l15;
                    float bv = bias[c];
                    #pragma unroll
                    for (int i = 0; i < 4; ++i) {
                        int row = row0 + g * 4 + i;
                        dst[row * 256 + c] = f2bf(acc[j][i] + bv);
                    }
                }
            } else {
                int bq = row0 / 48, nb = row0 % 48;
                unsigned short* vt = p.VT + agg * 524288 + bq * 16384;
                #pragma unroll
                for (int j = 0; j < 4; ++j) {
                    int d = col0 + j * 16 + l15;
                    float bv = bias[d];
                    #pragma unroll
                    for (int i = 0; i < 4; ++i) {
                        int m = g * 4 + i;
                        vt[d * 64 + nb + m] = f2bf(acc[j][i] + bv);
                        if (rowtile % 3 == 2) vt[d * 64 + 48 + m] = 0;  // zero pad k=48..63
                    }
                }
            }
        } else {
            // fold: Wc = Wm @ Wo (bf16 out), bc = Wm @ bo
            int jid2 = job - 2304;
            int agg = jid2 >> 6, r2 = jid2 & 63;
            int ct16 = r2 >> 2, dt64 = r2 & 3;
            const float* Wm = agg ? p.sWm : p.aWm;
            const float* Wo = agg ? p.sWo : p.aWo;
            const float* bo = agg ? p.sbo : p.abo;
            const float* Wmp = Wm + (ct16 * 16 + l15) * 256 + l16;
            f32x4 acc[4] = {{0,0,0,0},{0,0,0,0},{0,0,0,0},{0,0,0,0}};
            for (int kk = 0; kk < 8; ++kk) {
                short8v a = cvt8(Wmp + kk * 32);
                #pragma unroll
                for (int jf = 0; jf < 4; ++jf) {
                    union { unsigned short u[8]; short8v s; } bf;
                    #pragma unroll
                    for (int jj = 0; jj < 8; ++jj)
                        bf.u[jj] = f2bf(Wo[(kk * 32 + l16 + jj) * 256 + dt64 * 64 + jf * 16 + l15]);
                    acc[jf] = __builtin_amdgcn_mfma_f32_16x16x32_bf16(a, bf.s, acc[jf], 0, 0, 0);
                }
            }
            unsigned short* Wcb = p.Wcb + agg * 65536;
            #pragma unroll
            for (int jf = 0; jf < 4; ++jf)
                #pragma unroll
                for (int i = 0; i < 4; ++i)
                    Wcb[(ct16 * 16 + g * 4 + i) * 256 + dt64 * 64 + jf * 16 + l15] = f2bf(acc[jf][i]);
            if (dt64 == 0) {
                const float* wmr = Wm + (ct16 * 16 + l15) * 256 + g * 64;
                const float* bor = bo + g * 64;
                float s = 0.f;
                #pragma unroll
                for (int i2 = 0; i2 < 64; ++i2) s += wmr[i2] * bor[i2];
                s += __shfl_xor(s, 16);
                s += __shfl_xor(s, 32);
                if (g == 0) p.bc[agg * 256 + ct16 * 16 + l15] = s;
            }
        }
    }

    cg::this_grid().sync();

    // ================= Phase 1: scores -> Eg (once, 1 job/wave) =================
    {
        int agg = w / 768, r = w % 768;
        int b = r / 24, j24 = r % 24, h = j24 / 3, qt = j24 % 3;
        const unsigned short* Qbp = p.Qb + agg * 393216;
        const unsigned short* Kbp = p.Kb + agg * 393216;
        short8v a = ld8(Qbp + (b * 48 + qt * 16 + l15) * 256 + h * 32 + l16);
        f32x4 acc[3];
        #pragma unroll
        for (int kt = 0; kt < 3; ++kt) {
            short8v kb = ld8(Kbp + (b * 48 + kt * 16 + l15) * 256 + h * 32 + l16);
            f32x4 z = {0.f, 0.f, 0.f, 0.f};
            acc[kt] = __builtin_amdgcn_mfma_f32_16x16x32_bf16(a, kb, z, 0, 0, 0);
        }
        const float scale = 0.17677669529663687f;  // 1/sqrt(32)
        float sc[3][4], rm[4];
        #pragma unroll
        for (int i = 0; i < 4; ++i) {
            #pragma unroll
            for (int kt = 0; kt < 3; ++kt) sc[kt][i] = acc[kt][i] * scale;
            rm[i] = fmaxf(fmaxf(sc[0][i], sc[1][i]), sc[2][i]);
        }
        #pragma unroll
        for (int m = 1; m <= 8; m <<= 1)
            #pragma unroll
            for (int i = 0; i < 4; ++i) rm[i] = fmaxf(rm[i], __shfl_xor(rm[i], m));
        unsigned short* Egp = p.Eg + agg * 589824 + b * 18432 + h * 2304;
        #pragma unroll
        for (int kt = 0; kt < 3; ++kt)
            #pragma unroll
            for (int i = 0; i < 4; ++i)
                Egp[(qt * 16 + g * 4 + i) * 48 + kt * 16 + l15] =
                    f2bf(__expf(sc[kt][i] - rm[i]));
    }

    cg::this_grid().sync();

    // ================= Phase 2: aggregate + final, per (agg,b,12 targets) ========
    {
        int agg = bid >> 7, rem = bid & 127, b2 = rem >> 2, tg = rem & 3;
        int row_base = b2 * 48 + tg * 12;
        const float* fb = agg ? p.sync_fea : p.async_fea;
        const int* adj = agg ? p.async_adj : p.sync_adj;

        // passthrough copy (independent)
        {
            const float4* fb4 = (const float4*)fb;
            float4* out4 = (float4*)p.out;
            #pragma unroll
            for (int l = 0; l < 2; ++l) {
                int e = l * 384 + tid;
                int r = e >> 6, c = e & 63;
                out4[(row_base + r) * 256 + 128 + agg * 64 + c] =
                    fb4[(row_base + r) * 64 + c];
            }
        }

        // stage E row `tid` -> registers + E_l
        float erow[48];
        {
            const uint4* src = (const uint4*)(p.Eg + agg * 589824 + b2 * 18432 + tid * 48);
            uint* El_u = (uint*)E_l;
            #pragma unroll
            for (int v = 0; v < 6; ++v) {
                uint4 u4 = src[v];
                unsigned uu[4] = {u4.x, u4.y, u4.z, u4.w};
                #pragma unroll
                for (int c = 0; c < 4; ++c) {
                    El_u[tid * 25 + v * 4 + c] = uu[c];
                    union { unsigned u; float f; } lo, hi;
                    lo.u = uu[c] << 16;
                    hi.u = uu[c] & 0xFFFF0000u;
                    erow[v * 8 + c * 2]     = lo.f;
                    erow[v * 8 + c * 2 + 1] = hi.f;
                }
            }
        }
        // masks
        for (int e = tid; e < 576; e += 384) {
            int tt = e / 48, s = e % 48;
            msk[tt * 48 + s] = (adj[(b2 * 48 + s) * 48 + tg * 12 + tt] > 0) ? 1.f : 0.f;
        }
        // zero yv_b (incl. pads)
        {
            uint* yz = (uint*)yv_b;
            for (int e = tid; e < 4160; e += 384) yz[e] = 0u;
        }
        __syncthreads();
        if (tid < 12) {
            float c = 0.f;
            for (int s = 0; s < 48; ++s) c += msk[tid * 48 + s];
            cnt_l[tid] = c;
        }

        // Phase A: invd[tt][tid] = m[q] / (sum_k m[k]*E[row tid][k])
        {
            int q = tid % 48;
            #pragma unroll
            for (int tt = 0; tt < 12; ++tt) {
                const float4* m4p = (const float4*)&msk[tt * 48];
                float ss = 0.f;
                #pragma unroll
                for (int k4 = 0; k4 < 12; ++k4) {
                    float4 m4 = m4p[k4];
                    ss += m4.x * erow[4 * k4] + m4.y * erow[4 * k4 + 1]
                        + m4.z * erow[4 * k4 + 2] + m4.w * erow[4 * k4 + 3];
                }
                invd[tt * 384 + tid] = (msk[tt * 48 + q] > 0.f) ? (1.f / ss) : 0.f;
            }
        }
        __syncthreads();

        // Phase B: yv[tt][h,k] = m[k] * sum_q E[h,q,k]*invd[tt][h,q]  -> bf16
        {
            int h2 = tid / 48, k = tid % 48;
            float ecol[48];
            #pragma unroll
            for (int q = 0; q < 48; ++q) ecol[q] = bf2f(E_l[(h2 * 48 + q) * 50 + k]);
            #pragma unroll
            for (int tt = 0; tt < 12; ++tt) {
                const float4* iv4 = (const float4*)&invd[tt * 384 + h2 * 48];
                float ss = 0.f;
                #pragma unroll
                for (int q4 = 0; q4 < 12; ++q4) {
                    float4 v = iv4[q4];
                    ss += v.x * ecol[4 * q4] + v.y * ecol[4 * q4 + 1]
                        + v.z * ecol[4 * q4 + 2] + v.w * ecol[4 * q4 + 3];
                }
                yv_b[tt * 520 + h2 * 64 + k] = f2bf(msk[tt * 48 + k] * ss);
            }
        }
        __syncthreads();

        // Phase C: P = yv @ V via MFMA (VT global frags), 16 d-tile jobs
        for (int dt = wave; dt < 16; dt += 6) {
            int h = dt >> 1;
            int d = dt * 16 + l15;
            const unsigned short* yb = yv_b + l15 * 520 + h * 64;
            short8v a0 = ld8(yb + l16);
            short8v a1 = ld8(yb + 32 + l16);
            const unsigned short* vtp = p.VT + agg * 524288 + (b2 * 256 + d) * 64;
            short8v b0 = ld8(vtp + l16);
            short8v b1 = ld8(vtp + 32 + l16);
            f32x4 acc = {0.f, 0.f, 0.f, 0.f};
            acc = __builtin_amdgcn_mfma_f32_16x16x32_bf16(a0, b0, acc, 0, 0, 0);
            acc = __builtin_amdgcn_mfma_f32_16x16x32_bf16(a1, b1, acc, 0, 0, 0);
            #pragma unroll
            for (int i = 0; i < 4; ++i)
                P_lds[(g * 4 + i) * 264 + dt * 16 + l15] = f2bf(acc[i]);
        }
        __syncthreads();

        // Final GEMM: out = P @ Wc^T / cnt^2 + bc/cnt + bm (or fallback)
        const unsigned short* Wcb = p.Wcb + agg * 65536;
        const float* bc = p.bc + agg * 256;
        const float* bm = agg ? p.sbm : p.abm;
        for (int ct = wave; ct < 16; ct += 6) {
            f32x4 acc = {0.f, 0.f, 0.f, 0.f};
            const unsigned short* Wp = Wcb + (ct * 16 + l15) * 256 + l16;
            const unsigned short* Pp = P_lds + l15 * 264 + l16;
            #pragma unroll
            for (int kk = 0; kk < 8; ++kk) {
                short8v a = ld8(Pp + kk * 32);
                short8v bfr = ld8(Wp + kk * 32);
                acc = __builtin_amdgcn_mfma_f32_16x16x32_bf16(a, bfr, acc, 0, 0, 0);
            }
            int c = ct * 16 + l15;
            float bcv = bc[c], bmv = bm[c];
            #pragma unroll
            for (int i = 0; i < 4; ++i) {
                int t = g * 4 + i;
                if (t < 12) {
                    int grow = row_base + t;
                    float cn = cnt_l[t];
                    float val;
                    if (cn > 0.f) {
                        float inv1 = 1.f / cn;
                        val = acc[i] * inv1 * inv1 + bcv * inv1 + bmv;
                    } else {
                        val = fb[grow * 256 + c];
                    }
                    p.out[grow * 1024 + agg * 256 + c] = val;
                }
            }
        }
    }
}

extern "C" void kernel_launch(void* const* d_in, const int* in_sizes, int n_in,
                              void* d_out, int out_size, void* d_ws, size_t ws_size,
                              hipStream_t stream)
{
    GigaParams p;
    p.async_fea = (const float*)d_in[0];
    p.sync_fea  = (const float*)d_in[1];
    p.async_adj = (const int*)d_in[2];
    p.sync_adj  = (const int*)d_in[3];
    p.aWq = (const float*)d_in[4];   p.abq = (const float*)d_in[5];
    p.aWk = (const float*)d_in[6];   p.abk = (const float*)d_in[7];
    p.aWv = (const float*)d_in[8];   p.abv = (const float*)d_in[9];
    p.aWo = (const float*)d_in[10];  p.abo = (const float*)d_in[11];
    p.aWm = (const float*)d_in[12];  p.abm = (const float*)d_in[13];
    p.sWq = (const float*)d_in[14];  p.sbq = (const float*)d_in[15];
    p.sWk = (const float*)d_in[16];  p.sbk = (const float*)d_in[17];
    p.sWv = (const float*)d_in[18];  p.sbv = (const float*)d_in[19];
    p.sWo = (const float*)d_in[20];  p.sbo = (const float*)d_in[21];
    p.sWm = (const float*)d_in[22];  p.sbm = (const float*)d_in[23];

    unsigned short* us = (unsigned short*)d_ws;
    p.Qb  = us;                    // 786432
    p.Kb  = p.Qb + 786432;         // 786432
    p.VT  = p.Kb + 786432;         // 1048576 ([agg][b][d][64], padded k)
    p.Wcb = p.VT + 1048576;        // 131072
    p.Eg  = p.Wcb + 131072;        // 1179648
    p.bc  = (float*)(p.Eg + 1179648);  // 512 floats
    p.out = (float*)d_out;

    void* args[] = { &p };
    hipLaunchCooperativeKernel((void*)giga_kernel, dim3(256), dim3(384),
                               args, 0, stream);
}

// Round 7
// 59.995 us; speedup vs baseline: 2.2082x; 2.2082x over previous
//
#include <hip/hip_runtime.h>

typedef __attribute__((ext_vector_type(8))) short short8v;   // 8 bf16
typedef __attribute__((ext_vector_type(4))) float f32x4;

#define XPAD 264   // bf16 row pitch for 256-wide LDS tiles
#define ESTR 52    // bf16 row pitch for E (48 wide)

// fp32 -> bf16 RNE (scalar)
__device__ __forceinline__ unsigned short f2bf(float f) {
    union { float f; unsigned u; } v; v.f = f;
    unsigned u = v.u;
    return (unsigned short)((u + 0x7FFFu + ((u >> 16) & 1u)) >> 16);
}
__device__ __forceinline__ float bf2f(unsigned short u) {
    union { unsigned u; float f; } v; v.u = ((unsigned)u) << 16; return v.f;
}
// 8 consecutive fp32 (32B-aligned) -> bf16x8 fragment
__device__ __forceinline__ short8v cvt8(const float* p) {
    float4 lo = *(const float4*)p;
    float4 hi = *(const float4*)(p + 4);
    union { uint4 u; short8v s; } r;
    asm("v_cvt_pk_bf16_f32 %0, %1, %2" : "=v"(r.u.x) : "v"(lo.x), "v"(lo.y));
    asm("v_cvt_pk_bf16_f32 %0, %1, %2" : "=v"(r.u.y) : "v"(lo.z), "v"(lo.w));
    asm("v_cvt_pk_bf16_f32 %0, %1, %2" : "=v"(r.u.z) : "v"(hi.x), "v"(hi.y));
    asm("v_cvt_pk_bf16_f32 %0, %1, %2" : "=v"(r.u.w) : "v"(hi.z), "v"(hi.w));
    return r.s;
}

struct AggParams {
    const float *async_fea, *sync_fea;
    const int *async_adj, *sync_adj;
    const float *aWq, *abq, *aWk, *abk, *aWv, *abv, *aWo, *abo, *aWm, *abm;
    const float *sWq, *sbq, *sWk, *sbk, *sWv, *sbv, *sWo, *sbo, *sWm, *sbm;
    float *out;
};

// One block = (agg, b, group of 12 targets). Fully independent blocks:
// redundantly computes QKV + scores for its (agg,b); no cross-block data.
__global__ __launch_bounds__(512) void block_kernel(AggParams p)
{
    // Time-multiplexed LDS regions (total 118,336 B -> 1 block/CU):
    //  [0)        E_l (39,936) | Xb (25,344)     Xb dead before E written
    //  [39,936)   Qb (25,344)  | invd (18,432)   Qb dead before invd written
    //  [65,280)   Kb (25,344)  | yv 9,312 + P_l 8,448
    //  [90,624)   Vb (25,344)  | pool_l (8,448)  Vb dead before pool written
    //  [115,968)  msk (2,304); [118,272) cnt (64)
    __shared__ __attribute__((aligned(16))) char sm[118336];
    unsigned short* E_l  = (unsigned short*)(sm);
    unsigned short* Xb   = (unsigned short*)(sm);
    unsigned short* Qb   = (unsigned short*)(sm + 39936);
    float*          invd = (float*)(sm + 39936);
    unsigned short* Kb   = (unsigned short*)(sm + 65280);
    unsigned short* yv   = (unsigned short*)(sm + 65280);
    unsigned short* P_l  = (unsigned short*)(sm + 74592);
    unsigned short* Vb   = (unsigned short*)(sm + 90624);
    unsigned short* pool_l = (unsigned short*)(sm + 90624);
    float* msk   = (float*)(sm + 115968);
    float* cnt_l = (float*)(sm + 118272);

    const int bid = blockIdx.x, tid = threadIdx.x;
    const int agg = bid >> 7, rem = bid & 127;
    const int b = rem >> 2, tg = rem & 3;
    const int wave = tid >> 6, lane = tid & 63;
    const int l15 = lane & 15, g = lane >> 4;
    const int row_base = b * 48 + tg * 12;

    const float* Xsrc = agg ? p.async_fea : p.sync_fea;   // source features
    const float* fb   = agg ? p.sync_fea  : p.async_fea;  // fallback / passthrough
    const int*   adj  = agg ? p.async_adj : p.sync_adj;

    // ---------------- Phase 0: X->LDS bf16, masks, passthrough ----------------
    #pragma unroll
    for (int l = 0; l < 3; ++l) {
        int idx = l * 4096 + tid * 8;            // 12288 elems
        int row = idx >> 8, col = idx & 255;
        short8v v = cvt8(Xsrc + (b * 48 + row) * 256 + col);
        *(short8v*)(Xb + row * XPAD + col) = v;
    }
    for (int e = tid; e < 576; e += 512) {
        int tt = e / 48, s = e % 48;
        msk[tt * 48 + s] = (adj[(b * 48 + s) * 48 + tg * 12 + tt] > 0) ? 1.f : 0.f;
    }
    {
        const float4* fb4 = (const float4*)fb;
        float4* out4 = (float4*)p.out;
        for (int e = tid; e < 768; e += 512) {
            int r = e >> 6, c = e & 63;
            out4[(row_base + r) * 256 + 128 + agg * 64 + c] =
                fb4[(row_base + r) * 64 + c];
        }
    }
    __syncthreads();                                             // B1
    if (tid < 12) {
        float c = 0.f;
        for (int s = 0; s < 48; ++s) c += msk[tid * 48 + s];
        cnt_l[tid] = c;
    }

    // ---------------- QKV: Xb(48x256) @ W^T, 48 col-jobs of 16 ----------------
    for (int job = wave; job < 48; job += 8) {
        int mat = job >> 4;                 // 0=Q 1=K 2=V
        int cm = (job & 15) * 16;
        const float* W; const float* bias;
        if (agg == 0) {
            W    = (mat == 0) ? p.aWq : (mat == 1) ? p.aWk : p.aWv;
            bias = (mat == 0) ? p.abq : (mat == 1) ? p.abk : p.abv;
        } else {
            W    = (mat == 0) ? p.sWq : (mat == 1) ? p.sWk : p.sWv;
            bias = (mat == 0) ? p.sbq : (mat == 1) ? p.sbk : p.sbv;
        }
        const float* Wp = W + (cm + l15) * 256 + g * 8;
        f32x4 acc[3] = {{0,0,0,0},{0,0,0,0},{0,0,0,0}};
        #pragma unroll
        for (int kk = 0; kk < 8; ++kk) {
            short8v bf = cvt8(Wp + kk * 32);
            #pragma unroll
            for (int rt = 0; rt < 3; ++rt) {
                short8v a = *(const short8v*)(Xb + (rt * 16 + l15) * XPAD + kk * 32 + g * 8);
                acc[rt] = __builtin_amdgcn_mfma_f32_16x16x32_bf16(a, bf, acc[rt], 0, 0, 0);
            }
        }
        float bv = bias[cm + l15];
        unsigned short* dst = (mat == 0) ? Qb : (mat == 1) ? Kb : Vb;
        #pragma unroll
        for (int rt = 0; rt < 3; ++rt)
            #pragma unroll
            for (int i = 0; i < 4; ++i) {
                int row = rt * 16 + g * 4 + i;
                dst[row * XPAD + cm + l15] = f2bf(acc[rt][i] + bv);
            }
    }
    __syncthreads();                                             // B2

    // ---------------- scores -> E_l bf16 (24 jobs: 8h x 3qt) ----------------
    const float scale = 0.17677669529663687f;  // 1/sqrt(32)
    #pragma unroll
    for (int jj = 0; jj < 3; ++jj) {
        int job = wave * 3 + jj;
        int h = job / 3, qt = job % 3;
        short8v a = *(const short8v*)(Qb + (qt * 16 + l15) * XPAD + h * 32 + g * 8);
        f32x4 acc[3];
        #pragma unroll
        for (int kt = 0; kt < 3; ++kt) {
            short8v kb = *(const short8v*)(Kb + (kt * 16 + l15) * XPAD + h * 32 + g * 8);
            f32x4 z = {0.f, 0.f, 0.f, 0.f};
            acc[kt] = __builtin_amdgcn_mfma_f32_16x16x32_bf16(a, kb, z, 0, 0, 0);
        }
        float sc[3][4], rm[4];
        #pragma unroll
        for (int i = 0; i < 4; ++i) {
            #pragma unroll
            for (int kt = 0; kt < 3; ++kt) sc[kt][i] = acc[kt][i] * scale;
            rm[i] = fmaxf(fmaxf(sc[0][i], sc[1][i]), sc[2][i]);
        }
        #pragma unroll
        for (int m = 1; m <= 8; m <<= 1)
            #pragma unroll
            for (int i = 0; i < 4; ++i) rm[i] = fmaxf(rm[i], __shfl_xor(rm[i], m));
        #pragma unroll
        for (int kt = 0; kt < 3; ++kt)
            #pragma unroll
            for (int i = 0; i < 4; ++i)
                E_l[(h * 48 + qt * 16 + g * 4 + i) * ESTR + kt * 16 + l15] =
                    f2bf(__expf(sc[kt][i] - rm[i]));
    }
    __syncthreads();                                             // B3

    // ---------------- Phase A: invd[tt][h*48+q] ----------------
    if (tid < 384) {
        float erow[48];
        const uint2* er = (const uint2*)(E_l + tid * ESTR);
        #pragma unroll
        for (int v = 0; v < 12; ++v) {
            uint2 u = er[v];
            erow[v * 4 + 0] = bf2f((unsigned short)(u.x & 0xFFFF));
            erow[v * 4 + 1] = bf2f((unsigned short)(u.x >> 16));
            erow[v * 4 + 2] = bf2f((unsigned short)(u.y & 0xFFFF));
            erow[v * 4 + 3] = bf2f((unsigned short)(u.y >> 16));
        }
        int q = tid % 48;
        #pragma unroll
        for (int tt = 0; tt < 12; ++tt) {
            const float4* m4p = (const float4*)&msk[tt * 48];
            float ss = 0.f;
            #pragma unroll
            for (int k4 = 0; k4 < 12; ++k4) {
                float4 m4 = m4p[k4];
                ss += m4.x * erow[4 * k4] + m4.y * erow[4 * k4 + 1]
                    + m4.z * erow[4 * k4 + 2] + m4.w * erow[4 * k4 + 3];
            }
            invd[tt * 384 + tid] = (msk[tt * 48 + q] > 0.f) ? (1.f / ss) : 0.f;
        }
    }
    __syncthreads();                                             // B4

    // ---------------- Phase B: yv[tt][h*48+k] bf16 ----------------
    if (tid < 384) {
        int h2 = tid / 48, k = tid % 48;
        float ecol[48];
        #pragma unroll
        for (int q = 0; q < 48; ++q) ecol[q] = bf2f(E_l[(h2 * 48 + q) * ESTR + k]);
        #pragma unroll
        for (int tt = 0; tt < 12; ++tt) {
            const float4* iv4 = (const float4*)&invd[tt * 384 + h2 * 48];
            float ss = 0.f;
            #pragma unroll
            for (int q4 = 0; q4 < 12; ++q4) {
                float4 v = iv4[q4];
                ss += v.x * ecol[4 * q4] + v.y * ecol[4 * q4 + 1]
                    + v.z * ecol[4 * q4 + 2] + v.w * ecol[4 * q4 + 3];
            }
            yv[tt * 388 + tid] = f2bf(msk[tt * 48 + k] * ss);
        }
    }
    __syncthreads();                                             // B5

    // ---------------- Phase C: P[tt][d] = sum_k yv*V -> P_l bf16 ----------------
    for (int e = tid; e < 1024; e += 512) {
        if (e < 768) {
            int tt = e >> 6, d4 = e & 63;
            const unsigned short* yr = yv + tt * 388 + (d4 >> 3) * 48;
            float px = 0.f, py = 0.f, pz = 0.f, pw = 0.f;
            #pragma unroll
            for (int k = 0; k < 48; ++k) {
                float yval = bf2f(yr[k]);
                uint2 vv = *(const uint2*)(Vb + k * XPAD + d4 * 4);
                px += yval * bf2f((unsigned short)(vv.x & 0xFFFF));
                py += yval * bf2f((unsigned short)(vv.x >> 16));
                pz += yval * bf2f((unsigned short)(vv.y & 0xFFFF));
                pw += yval * bf2f((unsigned short)(vv.y >> 16));
            }
            uint2 pk;
            pk.x = (unsigned)f2bf(px) | ((unsigned)f2bf(py) << 16);
            pk.y = (unsigned)f2bf(pz) | ((unsigned)f2bf(pw) << 16);
            *(uint2*)(P_l + tt * 264 + d4 * 4) = pk;
        } else {
            int e2 = e - 768;                    // zero rows 12..15
            int tt = 12 + (e2 >> 6), d4 = e2 & 63;
            uint2 z; z.x = 0u; z.y = 0u;
            *(uint2*)(P_l + tt * 264 + d4 * 4) = z;
        }
    }
    __syncthreads();                                             // B6

    // ---------------- GEMM-1: pooled = (P@Wo^T)/cnt^2 + bo/cnt -> bf16 ----------
    {
        const float* Wo = agg ? p.sWo : p.aWo;
        const float* bo = agg ? p.sbo : p.abo;
        for (int ct = wave; ct < 16; ct += 8) {
            f32x4 acc = {0.f, 0.f, 0.f, 0.f};
            const float* Wp = Wo + (ct * 16 + l15) * 256 + g * 8;
            #pragma unroll
            for (int kk = 0; kk < 8; ++kk) {
                short8v a = *(const short8v*)(P_l + l15 * 264 + kk * 32 + g * 8);
                short8v bf = cvt8(Wp + kk * 32);
                acc = __builtin_amdgcn_mfma_f32_16x16x32_bf16(a, bf, acc, 0, 0, 0);
            }
            int c = ct * 16 + l15;
            float bov = bo[c];
            #pragma unroll
            for (int i = 0; i < 4; ++i) {
                int t = g * 4 + i;
                float val = 0.f;
                if (t < 12) {
                    float cn = cnt_l[t];
                    float i1 = (cn > 0.f) ? 1.f / cn : 0.f;
                    val = acc[i] * i1 * i1 + bov * i1;
                }
                pool_l[t * 264 + c] = f2bf(val);
            }
        }
    }
    __syncthreads();                                             // B7

    // ---------------- GEMM-2: out = pooled@Wm^T + bm (or fallback) ----------
    {
        const float* Wm = agg ? p.sWm : p.aWm;
        const float* bm = agg ? p.sbm : p.abm;
        for (int ct = wave; ct < 16; ct += 8) {
            f32x4 acc = {0.f, 0.f, 0.f, 0.f};
            const float* Wp = Wm + (ct * 16 + l15) * 256 + g * 8;
            #pragma unroll
            for (int kk = 0; kk < 8; ++kk) {
                short8v a = *(const short8v*)(pool_l + l15 * 264 + kk * 32 + g * 8);
                short8v bf = cvt8(Wp + kk * 32);
                acc = __builtin_amdgcn_mfma_f32_16x16x32_bf16(a, bf, acc, 0, 0, 0);
            }
            int c = ct * 16 + l15;
            float bmv = bm[c];
            #pragma unroll
            for (int i = 0; i < 4; ++i) {
                int t = g * 4 + i;
                if (t < 12) {
                    int grow = row_base + t;
                    float cn = cnt_l[t];
                    float val = (cn > 0.f) ? (acc[i] + bmv) : fb[grow * 256 + c];
                    p.out[grow * 1024 + agg * 256 + c] = val;
                }
            }
        }
    }
}

extern "C" void kernel_launch(void* const* d_in, const int* in_sizes, int n_in,
                              void* d_out, int out_size, void* d_ws, size_t ws_size,
                              hipStream_t stream)
{
    AggParams p;
    p.async_fea = (const float*)d_in[0];
    p.sync_fea  = (const float*)d_in[1];
    p.async_adj = (const int*)d_in[2];
    p.sync_adj  = (const int*)d_in[3];
    p.aWq = (const float*)d_in[4];   p.abq = (const float*)d_in[5];
    p.aWk = (const float*)d_in[6];   p.abk = (const float*)d_in[7];
    p.aWv = (const float*)d_in[8];   p.abv = (const float*)d_in[9];
    p.aWo = (const float*)d_in[10];  p.abo = (const float*)d_in[11];
    p.aWm = (const float*)d_in[12];  p.abm = (const float*)d_in[13];
    p.sWq = (const float*)d_in[14];  p.sbq = (const float*)d_in[15];
    p.sWk = (const float*)d_in[16];  p.sbk = (const float*)d_in[17];
    p.sWv = (const float*)d_in[18];  p.sbv = (const float*)d_in[19];
    p.sWo = (const float*)d_in[20];  p.sbo = (const float*)d_in[21];
    p.sWm = (const float*)d_in[22];  p.sbm = (const float*)d_in[23];
    p.out = (float*)d_out;

    block_kernel<<<256, 512, 0, stream>>>(p);
}

// Round 8
// 53.981 us; speedup vs baseline: 2.4542x; 1.1114x over previous
//
#include <hip/hip_runtime.h>

typedef __attribute__((ext_vector_type(8))) short short8v;   // 8 bf16
typedef __attribute__((ext_vector_type(4))) float f32x4;
typedef unsigned short u16t;

#define XP 264      // pitch (elems) for Xb/Qb/Kb/P_l/pool: 528B rows, 16B-aligned
#define SP 52       // pitch (elems) for E/ET/VT/invd/yv/msk: 104B rows, odd banks

// LDS layout (bytes). Overlays: Xb->E region; invd,P_l->Qb; yv,pool->Kb.
#define E_OFF    0          // 384*52*2 = 39936   live [scores, A]
#define ET_OFF   39936      // 39936              live [scores, B]
#define QB_OFF   79872      // 48*264*2 = 25344   live [QKV, scores]
#define KB_OFF   105216     // 25344              live [QKV, scores]
#define VT_OFF   130560     // 256*52*2 = 26624   live [QKV, C]
#define MSK_OFF  157184     // 16*52*2 = 1664
#define CNT_OFF  158848     // 48
#define SM_SIZE  158912
#define XB_OFF   E_OFF               // Xb dead before E written
#define IV_OFF   QB_OFF              // invd 8*16*52*2 = 13312, after scores
#define PL_OFF   (QB_OFF + 13312)    // P_l 16*264*2 = 8448 (<= Qb end)
#define YV_OFF   KB_OFF              // yv 13312, after scores
#define PO_OFF   (KB_OFF + 13312)    // pool 8448 (<= Kb end)

__device__ __forceinline__ u16t f2bf(float f) {
    union { float f; unsigned u; } v; v.f = f;
    unsigned u = v.u;
    return (u16t)((u + 0x7FFFu + ((u >> 16) & 1u)) >> 16);
}
__device__ __forceinline__ float bf2f(u16t u) {
    union { unsigned u; float f; } v; v.u = ((unsigned)u) << 16; return v.f;
}
__device__ __forceinline__ short8v cvt8(const float* p) {
    float4 lo = *(const float4*)p;
    float4 hi = *(const float4*)(p + 4);
    union { uint4 u; short8v s; } r;
    asm("v_cvt_pk_bf16_f32 %0, %1, %2" : "=v"(r.u.x) : "v"(lo.x), "v"(lo.y));
    asm("v_cvt_pk_bf16_f32 %0, %1, %2" : "=v"(r.u.y) : "v"(lo.z), "v"(lo.w));
    asm("v_cvt_pk_bf16_f32 %0, %1, %2" : "=v"(r.u.z) : "v"(hi.x), "v"(hi.y));
    asm("v_cvt_pk_bf16_f32 %0, %1, %2" : "=v"(r.u.w) : "v"(hi.z), "v"(hi.w));
    return r.s;
}
// 8 bf16 from pitch-52 LDS tile (8B-aligned): two b64 loads
__device__ __forceinline__ short8v ld52(const u16t* p) {
    union { uint2 u[2]; short8v s; } r;
    r.u[0] = *(const uint2*)(p);
    r.u[1] = *(const uint2*)(p + 4);
    return r.s;
}

struct AggParams {
    const float *async_fea, *sync_fea;
    const int *async_adj, *sync_adj;
    const float *aWq, *abq, *aWk, *abk, *aWv, *abv, *aWo, *abo, *aWm, *abm;
    const float *sWq, *sbq, *sWk, *sbk, *sWv, *sbv, *sWo, *sbo, *sWm, *sbm;
    float *out;
};

// One block = (agg, b, group of 12 targets); fully independent blocks.
__global__ __launch_bounds__(512) void block_kernel(AggParams p)
{
    __shared__ __attribute__((aligned(16))) char sm[SM_SIZE];
    u16t* E_   = (u16t*)(sm + E_OFF);
    u16t* ET_  = (u16t*)(sm + ET_OFF);
    u16t* Xb   = (u16t*)(sm + XB_OFF);
    u16t* Qb   = (u16t*)(sm + QB_OFF);
    u16t* Kb   = (u16t*)(sm + KB_OFF);
    u16t* VT   = (u16t*)(sm + VT_OFF);
    u16t* mskb = (u16t*)(sm + MSK_OFF);
    u16t* iv_  = (u16t*)(sm + IV_OFF);
    u16t* yv_  = (u16t*)(sm + YV_OFF);
    u16t* P_l  = (u16t*)(sm + PL_OFF);
    u16t* po_  = (u16t*)(sm + PO_OFF);
    float* cnt_l = (float*)(sm + CNT_OFF);

    const int bid = blockIdx.x, tid = threadIdx.x;
    const int agg = bid >> 7, rem = bid & 127;
    const int b = rem >> 2, tg = rem & 3;
    const int wave = tid >> 6, lane = tid & 63;
    const int l15 = lane & 15, g = lane >> 4;
    const int row_base = b * 48 + tg * 12;

    const float* Xsrc = agg ? p.async_fea : p.sync_fea;
    const float* fb   = agg ? p.sync_fea  : p.async_fea;
    const int*   adj  = agg ? p.async_adj : p.sync_adj;

    // ---------------- P0: X->Xb bf16, masks, passthrough ----------------
    #pragma unroll
    for (int l = 0; l < 3; ++l) {
        int idx = l * 4096 + tid * 8;
        int row = idx >> 8, col = idx & 255;
        *(short8v*)(Xb + row * XP + col) = cvt8(Xsrc + (b * 48 + row) * 256 + col);
    }
    for (int e = tid; e < 16 * SP; e += 512) {
        int tt = e / SP, k = e - tt * SP;
        u16t v = 0;
        if (tt < 12 && k < 48)
            v = (adj[(b * 48 + k) * 48 + tg * 12 + tt] > 0) ? (u16t)0x3F80 : (u16t)0;
        mskb[e] = v;
    }
    {
        const float4* fb4 = (const float4*)fb;
        float4* out4 = (float4*)p.out;
        for (int e = tid; e < 768; e += 512) {
            int r = e >> 6, c = e & 63;
            out4[(row_base + r) * 256 + 128 + agg * 64 + c] =
                fb4[(row_base + r) * 64 + c];
        }
    }
    __syncthreads();                                             // B1
    if (tid < 12) {
        float c = 0.f;
        for (int s = 0; s < 48; ++s) c += bf2f(mskb[tid * SP + s]);
        cnt_l[tid] = c;
    }

    // ---------------- QKV: Xb(48x256) @ W^T -> Qb,Kb (row-major), VT (transposed) ----
    for (int job = wave; job < 48; job += 8) {
        int mat = job >> 4;                 // 0=Q 1=K 2=V
        int cm = (job & 15) * 16;
        const float* W; const float* bias;
        if (agg == 0) {
            W    = (mat == 0) ? p.aWq : (mat == 1) ? p.aWk : p.aWv;
            bias = (mat == 0) ? p.abq : (mat == 1) ? p.abk : p.abv;
        } else {
            W    = (mat == 0) ? p.sWq : (mat == 1) ? p.sWk : p.sWv;
            bias = (mat == 0) ? p.sbq : (mat == 1) ? p.sbk : p.sbv;
        }
        const float* Wp = W + (cm + l15) * 256 + g * 8;
        f32x4 acc[3] = {{0,0,0,0},{0,0,0,0},{0,0,0,0}};
        #pragma unroll
        for (int kk = 0; kk < 8; ++kk) {
            short8v bf = cvt8(Wp + kk * 32);
            #pragma unroll
            for (int rt = 0; rt < 3; ++rt) {
                short8v a = *(const short8v*)(Xb + (rt * 16 + l15) * XP + kk * 32 + g * 8);
                acc[rt] = __builtin_amdgcn_mfma_f32_16x16x32_bf16(a, bf, acc[rt], 0, 0, 0);
            }
        }
        float bv = bias[cm + l15];
        if (mat < 2) {
            u16t* dst = (mat == 0) ? Qb : Kb;
            #pragma unroll
            for (int rt = 0; rt < 3; ++rt)
                #pragma unroll
                for (int i = 0; i < 4; ++i)
                    dst[(rt * 16 + g * 4 + i) * XP + cm + l15] = f2bf(acc[rt][i] + bv);
        } else {
            // VT[d][k]: d = cm+l15 (output col), k = token row
            #pragma unroll
            for (int rt = 0; rt < 3; ++rt)
                #pragma unroll
                for (int i = 0; i < 4; ++i)
                    VT[(cm + l15) * SP + rt * 16 + g * 4 + i] = f2bf(acc[rt][i] + bv);
        }
    }
    __syncthreads();                                             // B2

    // ---------------- scores -> E (row-major) and ET (transposed), bf16 --------
    const float scale = 0.17677669529663687f;  // 1/sqrt(32)
    #pragma unroll
    for (int jj = 0; jj < 3; ++jj) {
        int job = wave * 3 + jj;            // 0..23
        int h = job / 3, qt = job % 3;
        short8v a = *(const short8v*)(Qb + (qt * 16 + l15) * XP + h * 32 + g * 8);
        f32x4 acc[3];
        #pragma unroll
        for (int kt = 0; kt < 3; ++kt) {
            short8v kb = *(const short8v*)(Kb + (kt * 16 + l15) * XP + h * 32 + g * 8);
            f32x4 z = {0.f, 0.f, 0.f, 0.f};
            acc[kt] = __builtin_amdgcn_mfma_f32_16x16x32_bf16(a, kb, z, 0, 0, 0);
        }
        float sc[3][4], rm[4];
        #pragma unroll
        for (int i = 0; i < 4; ++i) {
            #pragma unroll
            for (int kt = 0; kt < 3; ++kt) sc[kt][i] = acc[kt][i] * scale;
            rm[i] = fmaxf(fmaxf(sc[0][i], sc[1][i]), sc[2][i]);
        }
        #pragma unroll
        for (int m = 1; m <= 8; m <<= 1)
            #pragma unroll
            for (int i = 0; i < 4; ++i) rm[i] = fmaxf(rm[i], __shfl_xor(rm[i], m));
        #pragma unroll
        for (int kt = 0; kt < 3; ++kt)
            #pragma unroll
            for (int i = 0; i < 4; ++i) {
                u16t ev = f2bf(__expf(sc[kt][i] - rm[i]));
                int q = qt * 16 + g * 4 + i, k = kt * 16 + l15;
                E_[(h * 48 + q) * SP + k] = ev;
                ET_[(h * 48 + k) * SP + q] = ev;
            }
    }
    __syncthreads();                                             // B3

    // ---------------- Phase A (MFMA): D[row][tt] = sum_k E[row][k]*m[tt][k] ----
    // invd[tt][h,q] = m[tt][q] > 0 ? 1/D : 0   (bf16)
    #pragma unroll
    for (int jj = 0; jj < 3; ++jj) {
        int rt = wave * 3 + jj;             // 0..23 row tiles of 16
        const u16t* Arow = E_ + (rt * 16 + l15) * SP;
        const u16t* Brow = mskb + l15 * SP;
        f32x4 acc = {0.f, 0.f, 0.f, 0.f};
        short8v a0 = ld52(Arow + g * 8), b0 = ld52(Brow + g * 8);
        acc = __builtin_amdgcn_mfma_f32_16x16x32_bf16(a0, b0, acc, 0, 0, 0);
        short8v a1 = {0,0,0,0,0,0,0,0}, b1 = {0,0,0,0,0,0,0,0};
        if (g < 2) { a1 = ld52(Arow + 32 + g * 8); b1 = ld52(Brow + 32 + g * 8); }
        acc = __builtin_amdgcn_mfma_f32_16x16x32_bf16(a1, b1, acc, 0, 0, 0);
        #pragma unroll
        for (int i = 0; i < 4; ++i) {
            int row = rt * 16 + g * 4 + i;
            int h = row / 48, q = row - h * 48;
            float mq = bf2f(mskb[l15 * SP + q]);
            float ivv = (mq > 0.f) ? (1.f / acc[i]) : 0.f;
            iv_[(h * 16 + l15) * SP + q] = f2bf(ivv);
        }
    }
    __syncthreads();                                             // B4

    // ---------------- Phase B (MFMA): yv[tt][h,k] = m[k]*sum_q invd*ET ----------
    #pragma unroll
    for (int jj = 0; jj < 3; ++jj) {
        int job = wave * 3 + jj;            // (h, ktile)
        int h = job / 3, kt = job % 3;
        const u16t* Arow = iv_ + (h * 16 + l15) * SP;
        const u16t* Brow = ET_ + (h * 48 + kt * 16 + l15) * SP;
        f32x4 acc = {0.f, 0.f, 0.f, 0.f};
        short8v a0 = ld52(Arow + g * 8), b0 = ld52(Brow + g * 8);
        acc = __builtin_amdgcn_mfma_f32_16x16x32_bf16(a0, b0, acc, 0, 0, 0);
        short8v a1 = {0,0,0,0,0,0,0,0}, b1 = {0,0,0,0,0,0,0,0};
        if (g < 2) { a1 = ld52(Arow + 32 + g * 8); b1 = ld52(Brow + 32 + g * 8); }
        acc = __builtin_amdgcn_mfma_f32_16x16x32_bf16(a1, b1, acc, 0, 0, 0);
        #pragma unroll
        for (int i = 0; i < 4; ++i) {
            int tt = g * 4 + i, k = kt * 16 + l15;
            float mk = bf2f(mskb[tt * SP + k]);
            yv_[(h * 16 + tt) * SP + k] = f2bf(acc[i] * mk);
        }
    }
    __syncthreads();                                             // B5

    // ---------------- Phase C (MFMA): P[tt][d] = sum_k yv[tt][h,k]*VT[d][k] ----
    #pragma unroll
    for (int jj = 0; jj < 2; ++jj) {
        int job = wave * 2 + jj;            // 0..15: (h, dtile)
        int h = job >> 1, dt = job & 1;
        const u16t* Arow = yv_ + (h * 16 + l15) * SP;
        const u16t* Brow = VT + (h * 32 + dt * 16 + l15) * SP;
        f32x4 acc = {0.f, 0.f, 0.f, 0.f};
        short8v a0 = ld52(Arow + g * 8), b0 = ld52(Brow + g * 8);
        acc = __builtin_amdgcn_mfma_f32_16x16x32_bf16(a0, b0, acc, 0, 0, 0);
        short8v a1 = {0,0,0,0,0,0,0,0}, b1 = {0,0,0,0,0,0,0,0};
        if (g < 2) { a1 = ld52(Arow + 32 + g * 8); b1 = ld52(Brow + 32 + g * 8); }
        acc = __builtin_amdgcn_mfma_f32_16x16x32_bf16(a1, b1, acc, 0, 0, 0);
        #pragma unroll
        for (int i = 0; i < 4; ++i)
            P_l[(g * 4 + i) * XP + h * 32 + dt * 16 + l15] = f2bf(acc[i]);
    }
    __syncthreads();                                             // B6

    // ---------------- G1: pooled = (P@Wo^T)/cnt^2 + bo/cnt -> bf16 -------------
    {
        const float* Wo = agg ? p.sWo : p.aWo;
        const float* bo = agg ? p.sbo : p.abo;
        #pragma unroll
        for (int jj = 0; jj < 2; ++jj) {
            int ct = wave * 2 + jj;
            f32x4 acc = {0.f, 0.f, 0.f, 0.f};
            const float* Wp = Wo + (ct * 16 + l15) * 256 + g * 8;
            #pragma unroll
            for (int kk = 0; kk < 8; ++kk) {
                short8v a = *(const short8v*)(P_l + l15 * XP + kk * 32 + g * 8);
                short8v bf = cvt8(Wp + kk * 32);
                acc = __builtin_amdgcn_mfma_f32_16x16x32_bf16(a, bf, acc, 0, 0, 0);
            }
            int c = ct * 16 + l15;
            float bov = bo[c];
            #pragma unroll
            for (int i = 0; i < 4; ++i) {
                int t = g * 4 + i;
                float val = 0.f;
                if (t < 12) {
                    float cn = cnt_l[t];
                    float i1 = (cn > 0.f) ? 1.f / cn : 0.f;
                    val = acc[i] * i1 * i1 + bov * i1;
                }
                po_[t * XP + c] = f2bf(val);
            }
        }
    }
    __syncthreads();                                             // B7

    // ---------------- G2: out = pooled@Wm^T + bm (or fallback) -----------------
    {
        const float* Wm = agg ? p.sWm : p.aWm;
        const float* bm = agg ? p.sbm : p.abm;
        #pragma unroll
        for (int jj = 0; jj < 2; ++jj) {
            int ct = wave * 2 + jj;
            f32x4 acc = {0.f, 0.f, 0.f, 0.f};
            const float* Wp = Wm + (ct * 16 + l15) * 256 + g * 8;
            #pragma unroll
            for (int kk = 0; kk < 8; ++kk) {
                short8v a = *(const short8v*)(po_ + l15 * XP + kk * 32 + g * 8);
                short8v bf = cvt8(Wp + kk * 32);
                acc = __builtin_amdgcn_mfma_f32_16x16x32_bf16(a, bf, acc, 0, 0, 0);
            }
            int c = ct * 16 + l15;
            float bmv = bm[c];
            #pragma unroll
            for (int i = 0; i < 4; ++i) {
                int t = g * 4 + i;
                if (t < 12) {
                    int grow = row_base + t;
                    float cn = cnt_l[t];
                    float val = (cn > 0.f) ? (acc[i] + bmv) : fb[grow * 256 + c];
                    p.out[grow * 1024 + agg * 256 + c] = val;
                }
            }
        }
    }
}

extern "C" void kernel_launch(void* const* d_in, const int* in_sizes, int n_in,
                              void* d_out, int out_size, void* d_ws, size_t ws_size,
                              hipStream_t stream)
{
    AggParams p;
    p.async_fea = (const float*)d_in[0];
    p.sync_fea  = (const float*)d_in[1];
    p.async_adj = (const int*)d_in[2];
    p.sync_adj  = (const int*)d_in[3];
    p.aWq = (const float*)d_in[4];   p.abq = (const float*)d_in[5];
    p.aWk = (const float*)d_in[6];   p.abk = (const float*)d_in[7];
    p.aWv = (const float*)d_in[8];   p.abv = (const float*)d_in[9];
    p.aWo = (const float*)d_in[10];  p.abo = (const float*)d_in[11];
    p.aWm = (const float*)d_in[12];  p.abm = (const float*)d_in[13];
    p.sWq = (const float*)d_in[14];  p.sbq = (const float*)d_in[15];
    p.sWk = (const float*)d_in[16];  p.sbk = (const float*)d_in[17];
    p.sWv = (const float*)d_in[18];  p.sbv = (const float*)d_in[19];
    p.sWo = (const float*)d_in[20];  p.sbo = (const float*)d_in[21];
    p.sWm = (const float*)d_in[22];  p.sbm = (const float*)d_in[23];
    p.out = (float*)d_out;

    block_kernel<<<256, 512, 0, stream>>>(p);
}

// Round 10
// 53.051 us; speedup vs baseline: 2.4972x; 1.0175x over previous
//
#include <hip/hip_runtime.h>

typedef __attribute__((ext_vector_type(8))) short short8v;   // 8 bf16
typedef __attribute__((ext_vector_type(4))) float f32x4;
typedef unsigned short u16t;

#define XP 264      // pitch (elems) for Xb/Qb/Kb/P_l/pool: 528B rows, 16B-aligned, 2-way banks
#define SP 52       // pitch (elems) for E/ET/VT/invd/yv/msk: 104B rows, odd banks

// LDS layout (bytes). Overlays: Xb->E region; invd,P_l->Qb; yv,pool->Kb.
#define E_OFF    0          // 384*52*2 = 39936   live [scores, A]
#define ET_OFF   39936      // 39936              live [scores, B]
#define QB_OFF   79872      // 48*264*2 = 25344   live [QKV, scores]
#define KB_OFF   105216     // 25344              live [QKV, scores]
#define VT_OFF   130560     // 256*52*2 = 26624   live [QKV, C]
#define MSK_OFF  157184     // 16*52*2 = 1664
#define CNT_OFF  158848     // 48
#define SM_SIZE  158912
#define XB_OFF   E_OFF               // Xb dead before E written
#define IV_OFF   QB_OFF              // invd 8*16*52*2 = 13312, after scores
#define PL_OFF   (QB_OFF + 13312)    // P_l 16*264*2 = 8448 (<= Qb end)
#define YV_OFF   KB_OFF              // yv 13312, after scores
#define PO_OFF   (KB_OFF + 13312)    // pool 8448 (<= Kb end)

__device__ __forceinline__ u16t f2bf(float f) {
    union { float f; unsigned u; } v; v.f = f;
    unsigned u = v.u;
    return (u16t)((u + 0x7FFFu + ((u >> 16) & 1u)) >> 16);
}
__device__ __forceinline__ float bf2f(u16t u) {
    union { unsigned u; float f; } v; v.u = ((unsigned)u) << 16; return v.f;
}
__device__ __forceinline__ short8v cvt8(const float* p) {
    float4 lo = *(const float4*)p;
    float4 hi = *(const float4*)(p + 4);
    union { uint4 u; short8v s; } r;
    asm("v_cvt_pk_bf16_f32 %0, %1, %2" : "=v"(r.u.x) : "v"(lo.x), "v"(lo.y));
    asm("v_cvt_pk_bf16_f32 %0, %1, %2" : "=v"(r.u.y) : "v"(lo.z), "v"(lo.w));
    asm("v_cvt_pk_bf16_f32 %0, %1, %2" : "=v"(r.u.z) : "v"(hi.x), "v"(hi.y));
    asm("v_cvt_pk_bf16_f32 %0, %1, %2" : "=v"(r.u.w) : "v"(hi.z), "v"(hi.w));
    return r.s;
}
// 8 bf16 from pitch-52 LDS tile (8B-aligned): two b64 loads
__device__ __forceinline__ short8v ld52(const u16t* p) {
    union { uint2 u[2]; short8v s; } r;
    r.u[0] = *(const uint2*)(p);
    r.u[1] = *(const uint2*)(p + 4);
    return r.s;
}

struct AggParams {
    const float *async_fea, *sync_fea;
    const int *async_adj, *sync_adj;
    const float *aWq, *abq, *aWk, *abk, *aWv, *abv, *aWo, *abo, *aWm, *abm;
    const float *sWq, *sbq, *sWk, *sbk, *sWv, *sbv, *sWo, *sbo, *sWm, *sbm;
    float *out;
};

// One block = (agg, b, group of 12 targets); fully independent blocks.
// 512 threads (validated R8 structure); QKV B-fragments hoisted per wave.
__global__ __launch_bounds__(512) void block_kernel(AggParams p)
{
    __shared__ __attribute__((aligned(16))) char sm[SM_SIZE];
    u16t* E_   = (u16t*)(sm + E_OFF);
    u16t* ET_  = (u16t*)(sm + ET_OFF);
    u16t* Xb   = (u16t*)(sm + XB_OFF);
    u16t* Qb   = (u16t*)(sm + QB_OFF);
    u16t* Kb   = (u16t*)(sm + KB_OFF);
    u16t* VT   = (u16t*)(sm + VT_OFF);
    u16t* mskb = (u16t*)(sm + MSK_OFF);
    u16t* iv_  = (u16t*)(sm + IV_OFF);
    u16t* yv_  = (u16t*)(sm + YV_OFF);
    u16t* P_l  = (u16t*)(sm + PL_OFF);
    u16t* po_  = (u16t*)(sm + PO_OFF);
    float* cnt_l = (float*)(sm + CNT_OFF);

    const int bid = blockIdx.x, tid = threadIdx.x;
    const int agg = bid >> 7, rem = bid & 127;
    const int b = rem >> 2, tg = rem & 3;
    const int wave = tid >> 6, lane = tid & 63;
    const int l15 = lane & 15, g = lane >> 4;
    const int row_base = b * 48 + tg * 12;

    const float* Xsrc = agg ? p.async_fea : p.sync_fea;
    const float* fb   = agg ? p.sync_fea  : p.async_fea;
    const int*   adj  = agg ? p.async_adj : p.sync_adj;

    // ---------------- P0: X->Xb bf16, masks, passthrough ----------------
    #pragma unroll
    for (int l = 0; l < 3; ++l) {
        int idx = l * 4096 + tid * 8;
        int row = idx >> 8, col = idx & 255;
        *(short8v*)(Xb + row * XP + col) = cvt8(Xsrc + (b * 48 + row) * 256 + col);
    }
    for (int e = tid; e < 16 * SP; e += 512) {
        int tt = e / SP, k = e - tt * SP;
        u16t v = 0;
        if (tt < 12 && k < 48)
            v = (adj[(b * 48 + k) * 48 + tg * 12 + tt] > 0) ? (u16t)0x3F80 : (u16t)0;
        mskb[e] = v;
    }
    {
        const float4* fb4 = (const float4*)fb;
        float4* out4 = (float4*)p.out;
        for (int e = tid; e < 768; e += 512) {
            int r = e >> 6, c = e & 63;
            out4[(row_base + r) * 256 + 128 + agg * 64 + c] =
                fb4[(row_base + r) * 64 + c];
        }
    }
    __syncthreads();                                             // B1
    if (tid < 12) {
        float c = 0.f;
        for (int s = 0; s < 48; ++s) c += bf2f(mskb[tid * SP + s]);
        cnt_l[tid] = c;
    }

    // ---------------- QKV: Xb(48x256) @ {Wq,Wk,Wv}^T, B-frags hoisted ----------
    // Per wave: 2 cm-tiles; per tile load all 24 W-frags once, reuse each X-frag 3x.
    {
        const float *Wq, *Wk, *Wv, *bq, *bk, *bv;
        if (agg == 0) { Wq = p.aWq; Wk = p.aWk; Wv = p.aWv; bq = p.abq; bk = p.abk; bv = p.abv; }
        else          { Wq = p.sWq; Wk = p.sWk; Wv = p.sWv; bq = p.sbq; bk = p.sbk; bv = p.sbv; }
        for (int cmi = wave; cmi < 16; cmi += 8) {
            int cm = cmi * 16;
            const float* Wqp = Wq + (cm + l15) * 256 + g * 8;
            const float* Wkp = Wk + (cm + l15) * 256 + g * 8;
            const float* Wvp = Wv + (cm + l15) * 256 + g * 8;
            short8v bqf[8], bkf[8], bvf[8];
            #pragma unroll
            for (int kk = 0; kk < 8; ++kk) {
                bqf[kk] = cvt8(Wqp + kk * 32);
                bkf[kk] = cvt8(Wkp + kk * 32);
                bvf[kk] = cvt8(Wvp + kk * 32);
            }
            f32x4 aq[3], ak[3], av[3];
            #pragma unroll
            for (int rt = 0; rt < 3; ++rt) {
                f32x4 z = {0.f, 0.f, 0.f, 0.f};
                aq[rt] = z; ak[rt] = z; av[rt] = z;
            }
            #pragma unroll
            for (int rt = 0; rt < 3; ++rt)
                #pragma unroll
                for (int kk = 0; kk < 8; ++kk) {
                    short8v a = *(const short8v*)(Xb + (rt * 16 + l15) * XP + kk * 32 + g * 8);
                    aq[rt] = __builtin_amdgcn_mfma_f32_16x16x32_bf16(a, bqf[kk], aq[rt], 0, 0, 0);
                    ak[rt] = __builtin_amdgcn_mfma_f32_16x16x32_bf16(a, bkf[kk], ak[rt], 0, 0, 0);
                    av[rt] = __builtin_amdgcn_mfma_f32_16x16x32_bf16(a, bvf[kk], av[rt], 0, 0, 0);
                }
            float bqv = bq[cm + l15], bkv = bk[cm + l15], bvv = bv[cm + l15];
            #pragma unroll
            for (int rt = 0; rt < 3; ++rt)
                #pragma unroll
                for (int i = 0; i < 4; ++i) {
                    int row = rt * 16 + g * 4 + i;
                    Qb[row * XP + cm + l15] = f2bf(aq[rt][i] + bqv);
                    Kb[row * XP + cm + l15] = f2bf(ak[rt][i] + bkv);
                    VT[(cm + l15) * SP + row] = f2bf(av[rt][i] + bvv);
                }
        }
    }
    __syncthreads();                                             // B2

    // ---------------- scores -> E (row-major) and ET (transposed), bf16 --------
    const float scale = 0.17677669529663687f;  // 1/sqrt(32)
    #pragma unroll
    for (int jj = 0; jj < 3; ++jj) {
        int job = wave * 3 + jj;            // 0..23
        int h = job / 3, qt = job % 3;
        short8v a = *(const short8v*)(Qb + (qt * 16 + l15) * XP + h * 32 + g * 8);
        f32x4 acc[3];
        #pragma unroll
        for (int kt = 0; kt < 3; ++kt) {
            short8v kb = *(const short8v*)(Kb + (kt * 16 + l15) * XP + h * 32 + g * 8);
            f32x4 z = {0.f, 0.f, 0.f, 0.f};
            acc[kt] = __builtin_amdgcn_mfma_f32_16x16x32_bf16(a, kb, z, 0, 0, 0);
        }
        float sc[3][4], rm[4];
        #pragma unroll
        for (int i = 0; i < 4; ++i) {
            #pragma unroll
            for (int kt = 0; kt < 3; ++kt) sc[kt][i] = acc[kt][i] * scale;
            rm[i] = fmaxf(fmaxf(sc[0][i], sc[1][i]), sc[2][i]);
        }
        #pragma unroll
        for (int m = 1; m <= 8; m <<= 1)
            #pragma unroll
            for (int i = 0; i < 4; ++i) rm[i] = fmaxf(rm[i], __shfl_xor(rm[i], m));
        #pragma unroll
        for (int kt = 0; kt < 3; ++kt)
            #pragma unroll
            for (int i = 0; i < 4; ++i) {
                u16t ev = f2bf(__expf(sc[kt][i] - rm[i]));
                int q = qt * 16 + g * 4 + i, k = kt * 16 + l15;
                E_[(h * 48 + q) * SP + k] = ev;
                ET_[(h * 48 + k) * SP + q] = ev;
            }
    }
    __syncthreads();                                             // B3

    // ---------------- Phase A (MFMA): D[row][tt] = sum_k E[row][k]*m[tt][k] ----
    #pragma unroll
    for (int jj = 0; jj < 3; ++jj) {
        int rt = wave * 3 + jj;             // 0..23 row tiles of 16
        const u16t* Arow = E_ + (rt * 16 + l15) * SP;
        const u16t* Brow = mskb + l15 * SP;
        f32x4 acc = {0.f, 0.f, 0.f, 0.f};
        short8v a0 = ld52(Arow + g * 8), b0 = ld52(Brow + g * 8);
        acc = __builtin_amdgcn_mfma_f32_16x16x32_bf16(a0, b0, acc, 0, 0, 0);
        short8v a1 = {0,0,0,0,0,0,0,0}, b1 = {0,0,0,0,0,0,0,0};
        if (g < 2) { a1 = ld52(Arow + 32 + g * 8); b1 = ld52(Brow + 32 + g * 8); }
        acc = __builtin_amdgcn_mfma_f32_16x16x32_bf16(a1, b1, acc, 0, 0, 0);
        #pragma unroll
        for (int i = 0; i < 4; ++i) {
            int row = rt * 16 + g * 4 + i;
            int h = row / 48, q = row - h * 48;
            float mq = bf2f(mskb[l15 * SP + q]);
            float ivv = (mq > 0.f) ? (1.f / acc[i]) : 0.f;
            iv_[(h * 16 + l15) * SP + q] = f2bf(ivv);
        }
    }
    __syncthreads();                                             // B4

    // ---------------- Phase B (MFMA): yv[tt][h,k] = m[k]*sum_q invd*ET ----------
    #pragma unroll
    for (int jj = 0; jj < 3; ++jj) {
        int job = wave * 3 + jj;            // (h, ktile)
        int h = job / 3, kt = job % 3;
        const u16t* Arow = iv_ + (h * 16 + l15) * SP;
        const u16t* Brow = ET_ + (h * 48 + kt * 16 + l15) * SP;
        f32x4 acc = {0.f, 0.f, 0.f, 0.f};
        short8v a0 = ld52(Arow + g * 8), b0 = ld52(Brow + g * 8);
        acc = __builtin_amdgcn_mfma_f32_16x16x32_bf16(a0, b0, acc, 0, 0, 0);
        short8v a1 = {0,0,0,0,0,0,0,0}, b1 = {0,0,0,0,0,0,0,0};
        if (g < 2) { a1 = ld52(Arow + 32 + g * 8); b1 = ld52(Brow + 32 + g * 8); }
        acc = __builtin_amdgcn_mfma_f32_16x16x32_bf16(a1, b1, acc, 0, 0, 0);
        #pragma unroll
        for (int i = 0; i < 4; ++i) {
            int tt = g * 4 + i, k = kt * 16 + l15;
            float mk = bf2f(mskb[tt * SP + k]);
            yv_[(h * 16 + tt) * SP + k] = f2bf(acc[i] * mk);
        }
    }
    __syncthreads();                                             // B5

    // ---------------- Phase C (MFMA): P[tt][d] = sum_k yv[tt][h,k]*VT[d][k] ----
    #pragma unroll
    for (int jj = 0; jj < 2; ++jj) {
        int job = wave * 2 + jj;            // 0..15: (h, dtile)
        int h = job >> 1, dt = job & 1;
        const u16t* Arow = yv_ + (h * 16 + l15) * SP;
        const u16t* Brow = VT + (h * 32 + dt * 16 + l15) * SP;
        f32x4 acc = {0.f, 0.f, 0.f, 0.f};
        short8v a0 = ld52(Arow + g * 8), b0 = ld52(Brow + g * 8);
        acc = __builtin_amdgcn_mfma_f32_16x16x32_bf16(a0, b0, acc, 0, 0, 0);
        short8v a1 = {0,0,0,0,0,0,0,0}, b1 = {0,0,0,0,0,0,0,0};
        if (g < 2) { a1 = ld52(Arow + 32 + g * 8); b1 = ld52(Brow + 32 + g * 8); }
        acc = __builtin_amdgcn_mfma_f32_16x16x32_bf16(a1, b1, acc, 0, 0, 0);
        #pragma unroll
        for (int i = 0; i < 4; ++i)
            P_l[(g * 4 + i) * XP + h * 32 + dt * 16 + l15] = f2bf(acc[i]);
    }
    __syncthreads();                                             // B6

    // ---------------- G1: pooled = (P@Wo^T)/cnt^2 + bo/cnt -> bf16 -------------
    {
        const float* Wo = agg ? p.sWo : p.aWo;
        const float* bo = agg ? p.sbo : p.abo;
        #pragma unroll
        for (int jj = 0; jj < 2; ++jj) {
            int ct = wave * 2 + jj;
            f32x4 acc = {0.f, 0.f, 0.f, 0.f};
            const float* Wp = Wo + (ct * 16 + l15) * 256 + g * 8;
            #pragma unroll
            for (int kk = 0; kk < 8; ++kk) {
                short8v a = *(const short8v*)(P_l + l15 * XP + kk * 32 + g * 8);
                short8v bf = cvt8(Wp + kk * 32);
                acc = __builtin_amdgcn_mfma_f32_16x16x32_bf16(a, bf, acc, 0, 0, 0);
            }
            int c = ct * 16 + l15;
            float bov = bo[c];
            #pragma unroll
            for (int i = 0; i < 4; ++i) {
                int t = g * 4 + i;
                float val = 0.f;
                if (t < 12) {
                    float cn = cnt_l[t];
                    float i1 = (cn > 0.f) ? 1.f / cn : 0.f;
                    val = acc[i] * i1 * i1 + bov * i1;
                }
                po_[t * XP + c] = f2bf(val);
            }
        }
    }
    __syncthreads();                                             // B7

    // ---------------- G2: out = pooled@Wm^T + bm (or fallback) -----------------
    {
        const float* Wm = agg ? p.sWm : p.aWm;
        const float* bm = agg ? p.sbm : p.abm;
        #pragma unroll
        for (int jj = 0; jj < 2; ++jj) {
            int ct = wave * 2 + jj;
            f32x4 acc = {0.f, 0.f, 0.f, 0.f};
            const float* Wp = Wm + (ct * 16 + l15) * 256 + g * 8;
            #pragma unroll
            for (int kk = 0; kk < 8; ++kk) {
                short8v a = *(const short8v*)(po_ + l15 * XP + kk * 32 + g * 8);
                short8v bf = cvt8(Wp + kk * 32);
                acc = __builtin_amdgcn_mfma_f32_16x16x32_bf16(a, bf, acc, 0, 0, 0);
            }
            int c = ct * 16 + l15;
            float bmv = bm[c];
            #pragma unroll
            for (int i = 0; i < 4; ++i) {
                int t = g * 4 + i;
                if (t < 12) {
                    int grow = row_base + t;
                    float cn = cnt_l[t];
                    float val = (cn > 0.f) ? (acc[i] + bmv) : fb[grow * 256 + c];
                    p.out[grow * 1024 + agg * 256 + c] = val;
                }
            }
        }
    }
}

extern "C" void kernel_launch(void* const* d_in, const int* in_sizes, int n_in,
                              void* d_out, int out_size, void* d_ws, size_t ws_size,
                              hipStream_t stream)
{
    AggParams p;
    p.async_fea = (const float*)d_in[0];
    p.sync_fea  = (const float*)d_in[1];
    p.async_adj = (const int*)d_in[2];
    p.sync_adj  = (const int*)d_in[3];
    p.aWq = (const float*)d_in[4];   p.abq = (const float*)d_in[5];
    p.aWk = (const float*)d_in[6];   p.abk = (const float*)d_in[7];
    p.aWv = (const float*)d_in[8];   p.abv = (const float*)d_in[9];
    p.aWo = (const float*)d_in[10];  p.abo = (const float*)d_in[11];
    p.aWm = (const float*)d_in[12];  p.abm = (const float*)d_in[13];
    p.sWq = (const float*)d_in[14];  p.sbq = (const float*)d_in[15];
    p.sWk = (const float*)d_in[16];  p.sbk = (const float*)d_in[17];
    p.sWv = (const float*)d_in[18];  p.sbv = (const float*)d_in[19];
    p.sWo = (const float*)d_in[20];  p.sbo = (const float*)d_in[21];
    p.sWm = (const float*)d_in[22];  p.sbm = (const float*)d_in[23];
    p.out = (float*)d_out;

    block_kernel<<<256, 512, 0, stream>>>(p);
}

// Round 11
// 52.981 us; speedup vs baseline: 2.5005x; 1.0013x over previous
//
#include <hip/hip_runtime.h>

typedef __attribute__((ext_vector_type(8))) short short8v;   // 8 bf16
typedef __attribute__((ext_vector_type(4))) float f32x4;
typedef unsigned short u16t;

__device__ __forceinline__ u16t f2bf(float f) {
    union { float f; unsigned u; } v; v.f = f;
    unsigned u = v.u;
    return (u16t)((u + 0x7FFFu + ((u >> 16) & 1u)) >> 16);
}
__device__ __forceinline__ float bf2f(u16t u) {
    union { unsigned u; float f; } v; v.u = ((unsigned)u) << 16; return v.f;
}
__device__ __forceinline__ short8v cvt8(const float* p) {
    float4 lo = *(const float4*)p;
    float4 hi = *(const float4*)(p + 4);
    union { uint4 u; short8v s; } r;
    asm("v_cvt_pk_bf16_f32 %0, %1, %2" : "=v"(r.u.x) : "v"(lo.x), "v"(lo.y));
    asm("v_cvt_pk_bf16_f32 %0, %1, %2" : "=v"(r.u.y) : "v"(lo.z), "v"(lo.w));
    asm("v_cvt_pk_bf16_f32 %0, %1, %2" : "=v"(r.u.z) : "v"(hi.x), "v"(hi.y));
    asm("v_cvt_pk_bf16_f32 %0, %1, %2" : "=v"(r.u.w) : "v"(hi.z), "v"(hi.w));
    return r.s;
}
// 8 bf16 from pitch-52 LDS tile (8B-aligned): two b64 loads
__device__ __forceinline__ short8v ld52(const u16t* p) {
    union { uint2 u[2]; short8v s; } r;
    r.u[0] = *(const uint2*)(p);
    r.u[1] = *(const uint2*)(p + 4);
    return r.s;
}

struct Params {
    const float *async_fea, *sync_fea;
    const int *async_adj, *sync_adj;
    const float *Wf[10];       // aWq,aWk,aWv,aWo,aWm, sWq,sWk,sWv,sWo,sWm (fp32)
    const float *bqkv[6];      // [agg*3+mat]: a{bq,bk,bv}, s{bq,bk,bv}
    const float *bo_[2], *bm_[2];
    u16t *Wb;                  // [10][256][256] bf16, (agg*5+mat)*65536
    u16t *Qb, *Kb, *Vb;        // [agg][1536][256] bf16 row-major (agg*393216)
    u16t *Eg, *ETg;            // [agg][b][h][48][48] bf16 ((agg*32+b)*18432 + h*2304)
    float *out;
};

// ---------- Launch 0: weights -> bf16 (320 blocks x 256 thr x 8 elems) ----------
__global__ __launch_bounds__(256) void convert_kernel(Params p)
{
    int g8 = (blockIdx.x * 256 + threadIdx.x) * 8;   // 0 .. 655,352
    int w = g8 >> 16;                                // uniform per block
    int off = g8 & 65535;
    *(short8v*)(p.Wb + g8) = cvt8(p.Wf[w] + off);
}

// ---------- Launch 1: QKV MFMA (576 blocks x 256 thr) ----------
// block: (agg, rowtile of 64, coltile of 64 over [Wq|Wk|Wv]); wave = 16-row strip.
__global__ __launch_bounds__(256) void qkv_kernel(Params p)
{
    int bid = blockIdx.x;
    int agg = bid / 288, rem = bid % 288;
    int rt = rem / 12, ct = rem % 12;
    int wave = threadIdx.x >> 6, lane = threadIdx.x & 63;
    int l15 = lane & 15, g = lane >> 4;
    int row0 = rt * 64 + wave * 16;
    int mat = ct >> 2;
    int cbase = (ct & 3) * 64;
    const float* X = agg ? p.async_fea : p.sync_fea;
    const float* Xp = X + (row0 + l15) * 256 + g * 8;
    const u16t* Wp = p.Wb + (agg * 5 + mat) * 65536 + (cbase + l15) * 256 + g * 8;
    f32x4 acc[4] = {{0,0,0,0},{0,0,0,0},{0,0,0,0},{0,0,0,0}};
    #pragma unroll
    for (int kk = 0; kk < 8; ++kk) {
        short8v a = cvt8(Xp + kk * 32);
        #pragma unroll
        for (int j = 0; j < 4; ++j) {
            short8v b = *(const short8v*)(Wp + j * 16 * 256 + kk * 32);
            acc[j] = __builtin_amdgcn_mfma_f32_16x16x32_bf16(a, b, acc[j], 0, 0, 0);
        }
    }
    const float* bias = p.bqkv[agg * 3 + mat];
    u16t* dst = ((mat == 0) ? p.Qb : (mat == 1) ? p.Kb : p.Vb) + agg * 393216;
    #pragma unroll
    for (int j = 0; j < 4; ++j) {
        int c = cbase + j * 16 + l15;
        float bv = bias[c];
        #pragma unroll
        for (int i = 0; i < 4; ++i) {
            int row = row0 + g * 4 + i;
            dst[row * 256 + c] = f2bf(acc[j][i] + bv);
        }
    }
}

// ---------- Launch 2: scores -> E, ET bf16 (512 blocks = (agg,b,h), 192 thr) ----
__global__ __launch_bounds__(192) void scores_kernel(Params p)
{
    int bid = blockIdx.x;
    int agg = bid >> 8, r = bid & 255, b = r >> 3, h = r & 7;
    int qt = threadIdx.x >> 6, lane = threadIdx.x & 63;
    int l15 = lane & 15, g = lane >> 4;
    const u16t* Qp = p.Qb + agg * 393216 + (b * 48 + qt * 16 + l15) * 256 + h * 32 + g * 8;
    short8v a = *(const short8v*)Qp;
    f32x4 acc[3];
    #pragma unroll
    for (int kt = 0; kt < 3; ++kt) {
        const u16t* Kp = p.Kb + agg * 393216 + (b * 48 + kt * 16 + l15) * 256 + h * 32 + g * 8;
        short8v kb = *(const short8v*)Kp;
        f32x4 z = {0.f, 0.f, 0.f, 0.f};
        acc[kt] = __builtin_amdgcn_mfma_f32_16x16x32_bf16(a, kb, z, 0, 0, 0);
    }
    const float scale = 0.17677669529663687f;  // 1/sqrt(32)
    float sc[3][4], rm[4];
    #pragma unroll
    for (int i = 0; i < 4; ++i) {
        #pragma unroll
        for (int kt = 0; kt < 3; ++kt) sc[kt][i] = acc[kt][i] * scale;
        rm[i] = fmaxf(fmaxf(sc[0][i], sc[1][i]), sc[2][i]);
    }
    #pragma unroll
    for (int m = 1; m <= 8; m <<= 1)
        #pragma unroll
        for (int i = 0; i < 4; ++i) rm[i] = fmaxf(rm[i], __shfl_xor(rm[i], m));
    u16t* Eb  = p.Eg  + (agg * 32 + b) * 18432 + h * 2304;
    u16t* ETb = p.ETg + (agg * 32 + b) * 18432 + h * 2304;
    #pragma unroll
    for (int kt = 0; kt < 3; ++kt)
        #pragma unroll
        for (int i = 0; i < 4; ++i) {
            u16t ev = f2bf(__expf(sc[kt][i] - rm[i]));
            int q = qt * 16 + g * 4 + i, k = kt * 16 + l15;
            Eb[q * 48 + k]  = ev;
            ETb[k * 48 + q] = ev;
        }
}

// ---------- Launch 3: aggregation (256 blocks = (agg,b,tg), 512 thr) ----------
// LDS 71,872 B -> 2 blocks/CU. E/ET/Wo/Wm read as direct global B/A-frags (L2-hot).
#define VT_OFF   0          // [256][52] u16 = 26,624
#define IV_OFF   26624      // [8*16][52] = 13,312
#define YV_OFF   39936      // 13,312
#define PL_OFF   53248      // [16][264] = 8,448
#define PO_OFF   61696      // 8,448
#define MSK_OFF  70144      // [16][52] = 1,664
#define CNT_OFF  71808      // 64
#define SM3_SIZE 71872
#define SP 52
#define XP 264

__global__ __launch_bounds__(512) void agg_kernel(Params p)
{
    __shared__ __attribute__((aligned(16))) char sm[SM3_SIZE];
    u16t* VT   = (u16t*)(sm + VT_OFF);
    u16t* iv_  = (u16t*)(sm + IV_OFF);
    u16t* yv_  = (u16t*)(sm + YV_OFF);
    u16t* P_l  = (u16t*)(sm + PL_OFF);
    u16t* po_  = (u16t*)(sm + PO_OFF);
    u16t* mskb = (u16t*)(sm + MSK_OFF);
    float* cnt_l = (float*)(sm + CNT_OFF);

    const int bid = blockIdx.x, tid = threadIdx.x;
    const int agg = bid >> 7, rem = bid & 127;
    const int b = rem >> 2, tg = rem & 3;
    const int wave = tid >> 6, lane = tid & 63;
    const int l15 = lane & 15, g = lane >> 4;
    const int row_base = b * 48 + tg * 12;

    const float* fb  = agg ? p.sync_fea  : p.async_fea;
    const int*   adj = agg ? p.async_adj : p.sync_adj;
    const u16t* Egb  = p.Eg  + (agg * 32 + b) * 18432;
    const u16t* ETb  = p.ETg + (agg * 32 + b) * 18432;

    // ---- stage VT (transpose V rows), masks, passthrough ----
    #pragma unroll
    for (int l = 0; l < 3; ++l) {
        int idx = l * 4096 + tid * 8;        // 12,288 elems
        int k = idx >> 8, d0 = idx & 255;
        uint4 v = *(const uint4*)(p.Vb + agg * 393216 + (b * 48 + k) * 256 + d0);
        const u16t* pv = (const u16t*)&v;
        #pragma unroll
        for (int j = 0; j < 8; ++j) VT[(d0 + j) * SP + k] = pv[j];
    }
    for (int e = tid; e < 16 * SP; e += 512) {
        int tt = e / SP, k = e - tt * SP;
        u16t v = 0;
        if (tt < 12 && k < 48)
            v = (adj[(b * 48 + k) * 48 + tg * 12 + tt] > 0) ? (u16t)0x3F80 : (u16t)0;
        mskb[e] = v;
    }
    {
        const float4* fb4 = (const float4*)fb;
        float4* out4 = (float4*)p.out;
        for (int e = tid; e < 768; e += 512) {
            int r = e >> 6, c = e & 63;
            out4[(row_base + r) * 256 + 128 + agg * 64 + c] =
                fb4[(row_base + r) * 64 + c];
        }
    }
    __syncthreads();                                             // B1
    if (tid < 12) {
        float c = 0.f;
        for (int s = 0; s < 48; ++s) c += bf2f(mskb[tid * SP + s]);
        cnt_l[tid] = c;
    }

    // ---- Phase A (MFMA): D[row][tt] = sum_k E[row][k]*m[tt][k]; iv = 1/D ----
    #pragma unroll
    for (int jj = 0; jj < 3; ++jj) {
        int rt = wave * 3 + jj;             // 0..23
        const u16t* Arow = Egb + (rt * 16 + l15) * 48;
        const u16t* Brow = mskb + l15 * SP;
        f32x4 acc = {0.f, 0.f, 0.f, 0.f};
        short8v a0 = *(const short8v*)(Arow + g * 8);
        short8v b0 = ld52(Brow + g * 8);
        acc = __builtin_amdgcn_mfma_f32_16x16x32_bf16(a0, b0, acc, 0, 0, 0);
        short8v a1 = {0,0,0,0,0,0,0,0}, b1 = {0,0,0,0,0,0,0,0};
        if (g < 2) { a1 = *(const short8v*)(Arow + 32 + g * 8); b1 = ld52(Brow + 32 + g * 8); }
        acc = __builtin_amdgcn_mfma_f32_16x16x32_bf16(a1, b1, acc, 0, 0, 0);
        #pragma unroll
        for (int i = 0; i < 4; ++i) {
            int row = rt * 16 + g * 4 + i;
            int h = row / 48, q = row - h * 48;
            float mq = bf2f(mskb[l15 * SP + q]);
            float ivv = (mq > 0.f) ? (1.f / acc[i]) : 0.f;
            iv_[(h * 16 + l15) * SP + q] = f2bf(ivv);
        }
    }
    __syncthreads();                                             // B2

    // ---- Phase B (MFMA): yv[tt][h,k] = m[k]*sum_q iv[tt][h,q]*ET[h,k,q] ----
    #pragma unroll
    for (int jj = 0; jj < 3; ++jj) {
        int job = wave * 3 + jj;            // (h, ktile)
        int h = job / 3, kt = job % 3;
        const u16t* Arow = iv_ + (h * 16 + l15) * SP;
        const u16t* Brow = ETb + (h * 48 + kt * 16 + l15) * 48;
        f32x4 acc = {0.f, 0.f, 0.f, 0.f};
        short8v a0 = ld52(Arow + g * 8);
        short8v b0 = *(const short8v*)(Brow + g * 8);
        acc = __builtin_amdgcn_mfma_f32_16x16x32_bf16(a0, b0, acc, 0, 0, 0);
        short8v a1 = {0,0,0,0,0,0,0,0}, b1 = {0,0,0,0,0,0,0,0};
        if (g < 2) { a1 = ld52(Arow + 32 + g * 8); b1 = *(const short8v*)(Brow + 32 + g * 8); }
        acc = __builtin_amdgcn_mfma_f32_16x16x32_bf16(a1, b1, acc, 0, 0, 0);
        #pragma unroll
        for (int i = 0; i < 4; ++i) {
            int tt = g * 4 + i, k = kt * 16 + l15;
            float mk = bf2f(mskb[tt * SP + k]);
            yv_[(h * 16 + tt) * SP + k] = f2bf(acc[i] * mk);
        }
    }
    __syncthreads();                                             // B3

    // ---- Phase C (MFMA): P[tt][d] = sum_k yv[tt][h,k]*VT[d][k] ----
    #pragma unroll
    for (int jj = 0; jj < 2; ++jj) {
        int job = wave * 2 + jj;            // 0..15: (h, dtile)
        int h = job >> 1, dt = job & 1;
        const u16t* Arow = yv_ + (h * 16 + l15) * SP;
        const u16t* Brow = VT + (h * 32 + dt * 16 + l15) * SP;
        f32x4 acc = {0.f, 0.f, 0.f, 0.f};
        short8v a0 = ld52(Arow + g * 8), b0 = ld52(Brow + g * 8);
        acc = __builtin_amdgcn_mfma_f32_16x16x32_bf16(a0, b0, acc, 0, 0, 0);
        short8v a1 = {0,0,0,0,0,0,0,0}, b1 = {0,0,0,0,0,0,0,0};
        if (g < 2) { a1 = ld52(Arow + 32 + g * 8); b1 = ld52(Brow + 32 + g * 8); }
        acc = __builtin_amdgcn_mfma_f32_16x16x32_bf16(a1, b1, acc, 0, 0, 0);
        #pragma unroll
        for (int i = 0; i < 4; ++i)
            P_l[(g * 4 + i) * XP + h * 32 + dt * 16 + l15] = f2bf(acc[i]);
    }
    __syncthreads();                                             // B4

    // ---- G1: pooled = (P@Wo^T)/cnt^2 + bo/cnt -> bf16 (Wo bf16 global) ----
    {
        const u16t* Wo = p.Wb + (agg * 5 + 3) * 65536;
        const float* bo = p.bo_[agg];
        #pragma unroll
        for (int jj = 0; jj < 2; ++jj) {
            int ct = wave * 2 + jj;
            f32x4 acc = {0.f, 0.f, 0.f, 0.f};
            const u16t* Wp = Wo + (ct * 16 + l15) * 256 + g * 8;
            #pragma unroll
            for (int kk = 0; kk < 8; ++kk) {
                short8v a = *(const short8v*)(P_l + l15 * XP + kk * 32 + g * 8);
                short8v bf = *(const short8v*)(Wp + kk * 32);
                acc = __builtin_amdgcn_mfma_f32_16x16x32_bf16(a, bf, acc, 0, 0, 0);
            }
            int c = ct * 16 + l15;
            float bov = bo[c];
            #pragma unroll
            for (int i = 0; i < 4; ++i) {
                int t = g * 4 + i;
                float val = 0.f;
                if (t < 12) {
                    float cn = cnt_l[t];
                    float i1 = (cn > 0.f) ? 1.f / cn : 0.f;
                    val = acc[i] * i1 * i1 + bov * i1;
                }
                po_[t * XP + c] = f2bf(val);
            }
        }
    }
    __syncthreads();                                             // B5

    // ---- G2: out = pooled@Wm^T + bm (or fallback) ----
    {
        const u16t* Wm = p.Wb + (agg * 5 + 4) * 65536;
        const float* bm = p.bm_[agg];
        #pragma unroll
        for (int jj = 0; jj < 2; ++jj) {
            int ct = wave * 2 + jj;
            f32x4 acc = {0.f, 0.f, 0.f, 0.f};
            const u16t* Wp = Wm + (ct * 16 + l15) * 256 + g * 8;
            #pragma unroll
            for (int kk = 0; kk < 8; ++kk) {
                short8v a = *(const short8v*)(po_ + l15 * XP + kk * 32 + g * 8);
                short8v bf = *(const short8v*)(Wp + kk * 32);
                acc = __builtin_amdgcn_mfma_f32_16x16x32_bf16(a, bf, acc, 0, 0, 0);
            }
            int c = ct * 16 + l15;
            float bmv = bm[c];
            #pragma unroll
            for (int i = 0; i < 4; ++i) {
                int t = g * 4 + i;
                if (t < 12) {
                    int grow = row_base + t;
                    float cn = cnt_l[t];
                    float val = (cn > 0.f) ? (acc[i] + bmv) : fb[grow * 256 + c];
                    p.out[grow * 1024 + agg * 256 + c] = val;
                }
            }
        }
    }
}

extern "C" void kernel_launch(void* const* d_in, const int* in_sizes, int n_in,
                              void* d_out, int out_size, void* d_ws, size_t ws_size,
                              hipStream_t stream)
{
    Params p;
    p.async_fea = (const float*)d_in[0];
    p.sync_fea  = (const float*)d_in[1];
    p.async_adj = (const int*)d_in[2];
    p.sync_adj  = (const int*)d_in[3];
    // Wf order: aWq,aWk,aWv,aWo,aWm, sWq,sWk,sWv,sWo,sWm
    p.Wf[0] = (const float*)d_in[4];   // aWq
    p.Wf[1] = (const float*)d_in[6];   // aWk
    p.Wf[2] = (const float*)d_in[8];   // aWv
    p.Wf[3] = (const float*)d_in[10];  // aWo
    p.Wf[4] = (const float*)d_in[12];  // aWm
    p.Wf[5] = (const float*)d_in[14];  // sWq
    p.Wf[6] = (const float*)d_in[16];  // sWk
    p.Wf[7] = (const float*)d_in[18];  // sWv
    p.Wf[8] = (const float*)d_in[20];  // sWo
    p.Wf[9] = (const float*)d_in[22];  // sWm
    p.bqkv[0] = (const float*)d_in[5];   // abq
    p.bqkv[1] = (const float*)d_in[7];   // abk
    p.bqkv[2] = (const float*)d_in[9];   // abv
    p.bqkv[3] = (const float*)d_in[15];  // sbq
    p.bqkv[4] = (const float*)d_in[17];  // sbk
    p.bqkv[5] = (const float*)d_in[19];  // sbv
    p.bo_[0] = (const float*)d_in[11];   // abo
    p.bo_[1] = (const float*)d_in[21];   // sbo
    p.bm_[0] = (const float*)d_in[13];   // abm
    p.bm_[1] = (const float*)d_in[23];   // sbm

    u16t* us = (u16t*)d_ws;
    p.Wb  = us;                    // 655,360
    p.Qb  = p.Wb + 655360;         // 786,432
    p.Kb  = p.Qb + 786432;         // 786,432
    p.Vb  = p.Kb + 786432;         // 786,432
    p.Eg  = p.Vb + 786432;         // 1,179,648
    p.ETg = p.Eg + 1179648;        // 1,179,648  (total 5,373,952 u16 = 10.75 MB)
    p.out = (float*)d_out;

    convert_kernel<<<320, 256, 0, stream>>>(p);
    qkv_kernel<<<576, 256, 0, stream>>>(p);
    scores_kernel<<<512, 192, 0, stream>>>(p);
    agg_kernel<<<256, 512, 0, stream>>>(p);
}

// Round 12
// 50.824 us; speedup vs baseline: 2.6066x; 1.0424x over previous
//
#include <hip/hip_runtime.h>

typedef __attribute__((ext_vector_type(8))) short short8v;   // 8 bf16
typedef __attribute__((ext_vector_type(4))) float f32x4;
typedef unsigned short u16t;

__device__ __forceinline__ u16t f2bf(float f) {
    union { float f; unsigned u; } v; v.f = f;
    unsigned u = v.u;
    return (u16t)((u + 0x7FFFu + ((u >> 16) & 1u)) >> 16);
}
__device__ __forceinline__ float bf2f(u16t u) {
    union { unsigned u; float f; } v; v.u = ((unsigned)u) << 16; return v.f;
}
__device__ __forceinline__ short8v cvt8(const float* p) {
    float4 lo = *(const float4*)p;
    float4 hi = *(const float4*)(p + 4);
    union { uint4 u; short8v s; } r;
    asm("v_cvt_pk_bf16_f32 %0, %1, %2" : "=v"(r.u.x) : "v"(lo.x), "v"(lo.y));
    asm("v_cvt_pk_bf16_f32 %0, %1, %2" : "=v"(r.u.y) : "v"(lo.z), "v"(lo.w));
    asm("v_cvt_pk_bf16_f32 %0, %1, %2" : "=v"(r.u.z) : "v"(hi.x), "v"(hi.y));
    asm("v_cvt_pk_bf16_f32 %0, %1, %2" : "=v"(r.u.w) : "v"(hi.z), "v"(hi.w));
    return r.s;
}
// 8 bf16 from pitch-52 LDS tile (8B-aligned): two b64 loads
__device__ __forceinline__ short8v ld52(const u16t* p) {
    union { uint2 u[2]; short8v s; } r;
    r.u[0] = *(const uint2*)(p);
    r.u[1] = *(const uint2*)(p + 4);
    return r.s;
}

struct Params {
    const float *async_fea, *sync_fea;
    const int *async_adj, *sync_adj;
    const float *Wf[10];       // aWq,aWk,aWv,aWo,aWm, sWq,sWk,sWv,sWo,sWm (fp32)
    const float *bqkv[6];      // [agg*3+mat]
    const float *bo_[2], *bm_[2];
    u16t *Wb;                  // [10][256][256] bf16
    u16t *Qb, *Kb;             // [agg][1536][256] bf16 row-major
    u16t *VTg;                 // [agg][32][256][48] bf16 (V transposed per batch)
    u16t *Eg, *ETg;            // [agg][b][h][48][48] bf16
    float *out;
};

// ---------- Launch 0: weights -> bf16 ----------
__global__ __launch_bounds__(256) void convert_kernel(Params p)
{
    int g8 = (blockIdx.x * 256 + threadIdx.x) * 8;
    int w = g8 >> 16;
    int off = g8 & 65535;
    *(short8v*)(p.Wb + g8) = cvt8(p.Wf[w] + off);
}

// ---------- Launch 1: QKV MFMA (576 blocks x 256 thr), XCD-swizzled ----------
// bid&7 -> XCD (HW round-robin). agg = XCD-half; same-XCD consecutive blocks share rt.
__global__ __launch_bounds__(256) void qkv_kernel(Params p)
{
    int bid = blockIdx.x;
    int xcd = bid & 7, idx = bid >> 3;        // idx 0..71
    int agg = xcd >> 2, xcd_in = xcd & 3;
    int ct = idx % 12, rt = (idx / 12) * 4 + xcd_in;   // rt 0..23
    int wave = threadIdx.x >> 6, lane = threadIdx.x & 63;
    int l15 = lane & 15, g = lane >> 4;
    int row0 = rt * 64 + wave * 16;
    int mat = ct >> 2;
    int cbase = (ct & 3) * 64;
    const float* X = agg ? p.async_fea : p.sync_fea;
    const float* Xp = X + (row0 + l15) * 256 + g * 8;
    const u16t* Wp = p.Wb + (agg * 5 + mat) * 65536 + (cbase + l15) * 256 + g * 8;
    f32x4 acc[4] = {{0,0,0,0},{0,0,0,0},{0,0,0,0},{0,0,0,0}};
    #pragma unroll
    for (int kk = 0; kk < 8; ++kk) {
        short8v a = cvt8(Xp + kk * 32);
        #pragma unroll
        for (int j = 0; j < 4; ++j) {
            short8v b = *(const short8v*)(Wp + j * 16 * 256 + kk * 32);
            acc[j] = __builtin_amdgcn_mfma_f32_16x16x32_bf16(a, b, acc[j], 0, 0, 0);
        }
    }
    const float* bias = p.bqkv[agg * 3 + mat];
    if (mat < 2) {
        u16t* dst = ((mat == 0) ? p.Qb : p.Kb) + agg * 393216;
        #pragma unroll
        for (int j = 0; j < 4; ++j) {
            int c = cbase + j * 16 + l15;
            float bv = bias[c];
            #pragma unroll
            for (int i = 0; i < 4; ++i) {
                int row = row0 + g * 4 + i;
                dst[row * 256 + c] = f2bf(acc[j][i] + bv);
            }
        }
    } else {
        // V transposed: VTg[agg][b][d][k]
        u16t* vt = p.VTg + agg * 393216;
        #pragma unroll
        for (int j = 0; j < 4; ++j) {
            int c = cbase + j * 16 + l15;
            float bv = bias[c];
            #pragma unroll
            for (int i = 0; i < 4; ++i) {
                int row = row0 + g * 4 + i;
                vt[(row / 48) * 12288 + c * 48 + (row % 48)] = f2bf(acc[j][i] + bv);
            }
        }
    }
}

// ---------- Launch 2: scores -> E, ET bf16 (512 blocks, 192 thr), XCD-swizzled ----
__global__ __launch_bounds__(192) void scores_kernel(Params p)
{
    int bid = blockIdx.x;
    int xcd = bid & 7, idx = bid >> 3;        // idx 0..63
    int agg = xcd >> 2, xcd_in = xcd & 3;
    int h = idx & 7, b = (idx >> 3) * 4 + xcd_in;
    int qt = threadIdx.x >> 6, lane = threadIdx.x & 63;
    int l15 = lane & 15, g = lane >> 4;
    const u16t* Qp = p.Qb + agg * 393216 + (b * 48 + qt * 16 + l15) * 256 + h * 32 + g * 8;
    short8v a = *(const short8v*)Qp;
    f32x4 acc[3];
    #pragma unroll
    for (int kt = 0; kt < 3; ++kt) {
        const u16t* Kp = p.Kb + agg * 393216 + (b * 48 + kt * 16 + l15) * 256 + h * 32 + g * 8;
        short8v kb = *(const short8v*)Kp;
        f32x4 z = {0.f, 0.f, 0.f, 0.f};
        acc[kt] = __builtin_amdgcn_mfma_f32_16x16x32_bf16(a, kb, z, 0, 0, 0);
    }
    const float scale = 0.17677669529663687f;  // 1/sqrt(32)
    float sc[3][4], rm[4];
    #pragma unroll
    for (int i = 0; i < 4; ++i) {
        #pragma unroll
        for (int kt = 0; kt < 3; ++kt) sc[kt][i] = acc[kt][i] * scale;
        rm[i] = fmaxf(fmaxf(sc[0][i], sc[1][i]), sc[2][i]);
    }
    #pragma unroll
    for (int m = 1; m <= 8; m <<= 1)
        #pragma unroll
        for (int i = 0; i < 4; ++i) rm[i] = fmaxf(rm[i], __shfl_xor(rm[i], m));
    u16t* Eb  = p.Eg  + (agg * 32 + b) * 18432 + h * 2304;
    u16t* ETb = p.ETg + (agg * 32 + b) * 18432 + h * 2304;
    #pragma unroll
    for (int kt = 0; kt < 3; ++kt)
        #pragma unroll
        for (int i = 0; i < 4; ++i) {
            u16t ev = f2bf(__expf(sc[kt][i] - rm[i]));
            int q = qt * 16 + g * 4 + i, k = kt * 16 + l15;
            Eb[q * 48 + k]  = ev;
            ETb[k * 48 + q] = ev;
        }
}

// ---------- Launch 3: aggregation (256 blocks, 512 thr), XCD-swizzled ----------
// LDS 36,800 B -> 4 blocks/CU (32 waves/CU). V/E/ET/Wo/Wm read as global frags.
#define IV_OFF   0          // [8*16][52] u16 = 13,312 (pool overlays after Phase B)
#define YV_OFF   13312      // 13,312
#define PL_OFF   26624      // [16][264] = 8,448
#define MSK_OFF  35072      // [16][52] = 1,664
#define CNT_OFF  36736      // 64
#define SM3_SIZE 36800
#define PO_OFF   IV_OFF     // pool 8,448 <= 13,312 (iv dead after Phase B)
#define SP 52
#define XP 264

__global__ __launch_bounds__(512) void agg_kernel(Params p)
{
    __shared__ __attribute__((aligned(16))) char sm[SM3_SIZE];
    u16t* iv_  = (u16t*)(sm + IV_OFF);
    u16t* yv_  = (u16t*)(sm + YV_OFF);
    u16t* P_l  = (u16t*)(sm + PL_OFF);
    u16t* po_  = (u16t*)(sm + PO_OFF);
    u16t* mskb = (u16t*)(sm + MSK_OFF);
    float* cnt_l = (float*)(sm + CNT_OFF);

    const int bid = blockIdx.x, tid = threadIdx.x;
    // bijective XCD map: agg0 -> XCDs 0-3, agg1 -> 4-7; all 4 tg of (agg,b) on one XCD.
    const int xcd = bid & 7, idx = bid >> 3;          // idx 0..31
    const int agg = xcd >> 2, xcd_in = xcd & 3;
    const int tg = idx >> 3, b = ((idx & 7) << 2) | xcd_in;
    const int wave = tid >> 6, lane = tid & 63;
    const int l15 = lane & 15, g = lane >> 4;
    const int row_base = b * 48 + tg * 12;

    const float* fb  = agg ? p.sync_fea  : p.async_fea;
    const int*   adj = agg ? p.async_adj : p.sync_adj;
    const u16t* Egb  = p.Eg  + (agg * 32 + b) * 18432;
    const u16t* ETb  = p.ETg + (agg * 32 + b) * 18432;
    const u16t* VTb  = p.VTg + agg * 393216 + b * 12288;

    // ---- masks + passthrough ----
    for (int e = tid; e < 16 * SP; e += 512) {
        int tt = e / SP, k = e - tt * SP;
        u16t v = 0;
        if (tt < 12 && k < 48)
            v = (adj[(b * 48 + k) * 48 + tg * 12 + tt] > 0) ? (u16t)0x3F80 : (u16t)0;
        mskb[e] = v;
    }
    {
        const float4* fb4 = (const float4*)fb;
        float4* out4 = (float4*)p.out;
        for (int e = tid; e < 768; e += 512) {
            int r = e >> 6, c = e & 63;
            out4[(row_base + r) * 256 + 128 + agg * 64 + c] =
                fb4[(row_base + r) * 64 + c];
        }
    }
    __syncthreads();                                             // B1
    if (tid < 12) {
        float c = 0.f;
        for (int s = 0; s < 48; ++s) c += bf2f(mskb[tid * SP + s]);
        cnt_l[tid] = c;
    }

    // ---- Phase A (MFMA): D[row][tt] = sum_k E[row][k]*m[tt][k]; iv = 1/D ----
    #pragma unroll
    for (int jj = 0; jj < 3; ++jj) {
        int rt = wave * 3 + jj;             // 0..23
        const u16t* Arow = Egb + (rt * 16 + l15) * 48;
        const u16t* Brow = mskb + l15 * SP;
        f32x4 acc = {0.f, 0.f, 0.f, 0.f};
        short8v a0 = *(const short8v*)(Arow + g * 8);
        short8v b0 = ld52(Brow + g * 8);
        acc = __builtin_amdgcn_mfma_f32_16x16x32_bf16(a0, b0, acc, 0, 0, 0);
        short8v a1 = {0,0,0,0,0,0,0,0}, b1 = {0,0,0,0,0,0,0,0};
        if (g < 2) { a1 = *(const short8v*)(Arow + 32 + g * 8); b1 = ld52(Brow + 32 + g * 8); }
        acc = __builtin_amdgcn_mfma_f32_16x16x32_bf16(a1, b1, acc, 0, 0, 0);
        #pragma unroll
        for (int i = 0; i < 4; ++i) {
            int row = rt * 16 + g * 4 + i;
            int h = row / 48, q = row - h * 48;
            float mq = bf2f(mskb[l15 * SP + q]);
            float ivv = (mq > 0.f) ? (1.f / acc[i]) : 0.f;
            iv_[(h * 16 + l15) * SP + q] = f2bf(ivv);
        }
    }
    __syncthreads();                                             // B2

    // ---- Phase B (MFMA): yv[tt][h,k] = m[k]*sum_q iv[tt][h,q]*ET[h,k,q] ----
    #pragma unroll
    for (int jj = 0; jj < 3; ++jj) {
        int job = wave * 3 + jj;            // (h, ktile)
        int h = job / 3, kt = job % 3;
        const u16t* Arow = iv_ + (h * 16 + l15) * SP;
        const u16t* Brow = ETb + (h * 48 + kt * 16 + l15) * 48;
        f32x4 acc = {0.f, 0.f, 0.f, 0.f};
        short8v a0 = ld52(Arow + g * 8);
        short8v b0 = *(const short8v*)(Brow + g * 8);
        acc = __builtin_amdgcn_mfma_f32_16x16x32_bf16(a0, b0, acc, 0, 0, 0);
        short8v a1 = {0,0,0,0,0,0,0,0}, b1 = {0,0,0,0,0,0,0,0};
        if (g < 2) { a1 = ld52(Arow + 32 + g * 8); b1 = *(const short8v*)(Brow + 32 + g * 8); }
        acc = __builtin_amdgcn_mfma_f32_16x16x32_bf16(a1, b1, acc, 0, 0, 0);
        #pragma unroll
        for (int i = 0; i < 4; ++i) {
            int tt = g * 4 + i, k = kt * 16 + l15;
            float mk = bf2f(mskb[tt * SP + k]);
            yv_[(h * 16 + tt) * SP + k] = f2bf(acc[i] * mk);
        }
    }
    __syncthreads();                                             // B3

    // ---- Phase C (MFMA): P[tt][d] = sum_k yv[tt][h,k]*VT[b][d][k] (global B) ----
    #pragma unroll
    for (int jj = 0; jj < 2; ++jj) {
        int job = wave * 2 + jj;            // 0..15: (h, dtile)
        int h = job >> 1, dt = job & 1;
        const u16t* Arow = yv_ + (h * 16 + l15) * SP;
        const u16t* Brow = VTb + (h * 32 + dt * 16 + l15) * 48;
        f32x4 acc = {0.f, 0.f, 0.f, 0.f};
        short8v a0 = ld52(Arow + g * 8);
        short8v b0 = *(const short8v*)(Brow + g * 8);
        acc = __builtin_amdgcn_mfma_f32_16x16x32_bf16(a0, b0, acc, 0, 0, 0);
        short8v a1 = {0,0,0,0,0,0,0,0}, b1 = {0,0,0,0,0,0,0,0};
        if (g < 2) { a1 = ld52(Arow + 32 + g * 8); b1 = *(const short8v*)(Brow + 32 + g * 8); }
        acc = __builtin_amdgcn_mfma_f32_16x16x32_bf16(a1, b1, acc, 0, 0, 0);
        #pragma unroll
        for (int i = 0; i < 4; ++i)
            P_l[(g * 4 + i) * XP + h * 32 + dt * 16 + l15] = f2bf(acc[i]);
    }
    __syncthreads();                                             // B4

    // ---- G1: pooled = (P@Wo^T)/cnt^2 + bo/cnt -> bf16 (Wo bf16 global) ----
    {
        const u16t* Wo = p.Wb + (agg * 5 + 3) * 65536;
        const float* bo = p.bo_[agg];
        #pragma unroll
        for (int jj = 0; jj < 2; ++jj) {
            int ct = wave * 2 + jj;
            f32x4 acc = {0.f, 0.f, 0.f, 0.f};
            const u16t* Wp = Wo + (ct * 16 + l15) * 256 + g * 8;
            #pragma unroll
            for (int kk = 0; kk < 8; ++kk) {
                short8v a = *(const short8v*)(P_l + l15 * XP + kk * 32 + g * 8);
                short8v bf = *(const short8v*)(Wp + kk * 32);
                acc = __builtin_amdgcn_mfma_f32_16x16x32_bf16(a, bf, acc, 0, 0, 0);
            }
            int c = ct * 16 + l15;
            float bov = bo[c];
            #pragma unroll
            for (int i = 0; i < 4; ++i) {
                int t = g * 4 + i;
                float val = 0.f;
                if (t < 12) {
                    float cn = cnt_l[t];
                    float i1 = (cn > 0.f) ? 1.f / cn : 0.f;
                    val = acc[i] * i1 * i1 + bov * i1;
                }
                po_[t * XP + c] = f2bf(val);
            }
        }
    }
    __syncthreads();                                             // B5

    // ---- G2: out = pooled@Wm^T + bm (or fallback) ----
    {
        const u16t* Wm = p.Wb + (agg * 5 + 4) * 65536;
        const float* bm = p.bm_[agg];
        #pragma unroll
        for (int jj = 0; jj < 2; ++jj) {
            int ct = wave * 2 + jj;
            f32x4 acc = {0.f, 0.f, 0.f, 0.f};
            const u16t* Wp = Wm + (ct * 16 + l15) * 256 + g * 8;
            #pragma unroll
            for (int kk = 0; kk < 8; ++kk) {
                short8v a = *(const short8v*)(po_ + l15 * XP + kk * 32 + g * 8);
                short8v bf = *(const short8v*)(Wp + kk * 32);
                acc = __builtin_amdgcn_mfma_f32_16x16x32_bf16(a, bf, acc, 0, 0, 0);
            }
            int c = ct * 16 + l15;
            float bmv = bm[c];
            #pragma unroll
            for (int i = 0; i < 4; ++i) {
                int t = g * 4 + i;
                if (t < 12) {
                    int grow = row_base + t;
                    float cn = cnt_l[t];
                    float val = (cn > 0.f) ? (acc[i] + bmv) : fb[grow * 256 + c];
                    p.out[grow * 1024 + agg * 256 + c] = val;
                }
            }
        }
    }
}

extern "C" void kernel_launch(void* const* d_in, const int* in_sizes, int n_in,
                              void* d_out, int out_size, void* d_ws, size_t ws_size,
                              hipStream_t stream)
{
    Params p;
    p.async_fea = (const float*)d_in[0];
    p.sync_fea  = (const float*)d_in[1];
    p.async_adj = (const int*)d_in[2];
    p.sync_adj  = (const int*)d_in[3];
    p.Wf[0] = (const float*)d_in[4];   // aWq
    p.Wf[1] = (const float*)d_in[6];   // aWk
    p.Wf[2] = (const float*)d_in[8];   // aWv
    p.Wf[3] = (const float*)d_in[10];  // aWo
    p.Wf[4] = (const float*)d_in[12];  // aWm
    p.Wf[5] = (const float*)d_in[14];  // sWq
    p.Wf[6] = (const float*)d_in[16];  // sWk
    p.Wf[7] = (const float*)d_in[18];  // sWv
    p.Wf[8] = (const float*)d_in[20];  // sWo
    p.Wf[9] = (const float*)d_in[22];  // sWm
    p.bqkv[0] = (const float*)d_in[5];   // abq
    p.bqkv[1] = (const float*)d_in[7];   // abk
    p.bqkv[2] = (const float*)d_in[9];   // abv
    p.bqkv[3] = (const float*)d_in[15];  // sbq
    p.bqkv[4] = (const float*)d_in[17];  // sbk
    p.bqkv[5] = (const float*)d_in[19];  // sbv
    p.bo_[0] = (const float*)d_in[11];   // abo
    p.bo_[1] = (const float*)d_in[21];   // sbo
    p.bm_[0] = (const float*)d_in[13];   // abm
    p.bm_[1] = (const float*)d_in[23];   // sbm

    u16t* us = (u16t*)d_ws;
    p.Wb  = us;                    // 655,360
    p.Qb  = p.Wb + 655360;         // 786,432
    p.Kb  = p.Qb + 786432;         // 786,432
    p.VTg = p.Kb + 786432;         // 786,432
    p.Eg  = p.VTg + 786432;        // 1,179,648
    p.ETg = p.Eg + 1179648;        // 1,179,648
    p.out = (float*)d_out;

    convert_kernel<<<320, 256, 0, stream>>>(p);
    qkv_kernel<<<576, 256, 0, stream>>>(p);
    scores_kernel<<<512, 192, 0, stream>>>(p);
    agg_kernel<<<256, 512, 0, stream>>>(p);
}